// Round 5
// baseline (1153.594 us; speedup 1.0000x reference)
//
#include <hip/hip_runtime.h>
#include <hip/hip_bf16.h>
#include <type_traits>

#define BB 32
#define AA 256
#define DD 512
#define HH 8
#define NLAYER 6
#define DFF 2048
#define NB 4

typedef float  f32x4_t  __attribute__((ext_vector_type(4)));
typedef short  bf16x8_t __attribute__((ext_vector_type(8)));

struct __align__(16) US8 { ushort u[8]; };

__device__ __forceinline__ ushort f2bf(float f) {
    __hip_bfloat16 h = __float2bfloat16(f);
    return *reinterpret_cast<ushort*>(&h);
}
__device__ __forceinline__ float bf2f(ushort u) {
    __hip_bfloat16 h;
    *reinterpret_cast<ushort*>(&h) = u;
    return __bfloat162float(h);
}

// async global->LDS, 16B per lane (dest linear: wave base + lane*16)
__device__ __forceinline__ void gload16(const void* g, void* l) {
    __builtin_amdgcn_global_load_lds(
        (const __attribute__((address_space(1))) void*)g,
        (__attribute__((address_space(3))) void*)l, 16, 0, 0);
}

template<int N> __device__ __forceinline__ void wait_vmcnt() {
    if constexpr      (N == 0)  asm volatile("s_waitcnt vmcnt(0)"  ::: "memory");
    else if constexpr (N == 3)  asm volatile("s_waitcnt vmcnt(3)"  ::: "memory");
    else if constexpr (N == 4)  asm volatile("s_waitcnt vmcnt(4)"  ::: "memory");
    else static_assert(N == 0, "add vmcnt literal");
}
template<int N> using ic = std::integral_constant<int, N>;

// ---------------------------------------------------------------------------
__global__ __launch_bounds__(256) void embed_pe_kernel(
    const int* __restrict__ src, const float* __restrict__ embed,
    const float* __restrict__ pe, float* __restrict__ x)
{
    int t = blockIdx.x * 256 + threadIdx.x;
    int d4 = t & 127;
    int row = t >> 7;
    int a = row & 255;
    int d = d4 * 4;
    int sub = d >> 6;
    int e = d & 63;
    int tok = src[row * 8 + sub];
    float4 em = *(const float4*)&embed[tok * 64 + e];
    float4 p  = *(const float4*)&pe[a * DD + d];
    const float s = 22.627416997969522f;  // sqrt(512)
    float4 r;
    r.x = em.x * s + p.x; r.y = em.y * s + p.y;
    r.z = em.z * s + p.z; r.w = em.w * s + p.w;
    *(float4*)&x[(long long)row * DD + d] = r;
}

// ---------------------------------------------------------------------------
template<bool OB>
__global__ __launch_bounds__(256) void layernorm512_kernel(
    const float* x, const float* __restrict__ alpha,
    const float* __restrict__ beta, void* yv)
{
    const int row = blockIdx.x * 4 + (threadIdx.x >> 6);
    const int lane = threadIdx.x & 63;
    const float* xr = x + (long long)row * DD;
    float4 v0 = *(const float4*)&xr[lane * 8];
    float4 v1 = *(const float4*)&xr[lane * 8 + 4];
    float s  = v0.x + v0.y + v0.z + v0.w + v1.x + v1.y + v1.z + v1.w;
    float ss = v0.x*v0.x + v0.y*v0.y + v0.z*v0.z + v0.w*v0.w
             + v1.x*v1.x + v1.y*v1.y + v1.z*v1.z + v1.w*v1.w;
    #pragma unroll
    for (int off = 1; off < 64; off <<= 1) {
        s  += __shfl_xor(s, off, 64);
        ss += __shfl_xor(ss, off, 64);
    }
    float mu = s * (1.0f / 512.0f);
    float var = fmaxf(ss - 512.0f * mu * mu, 0.0f) * (1.0f / 511.0f);
    float inv = 1.0f / (sqrtf(var) + 1e-6f);
    float4 a0 = *(const float4*)&alpha[lane * 8];
    float4 a1 = *(const float4*)&alpha[lane * 8 + 4];
    float4 b0 = *(const float4*)&beta[lane * 8];
    float4 b1 = *(const float4*)&beta[lane * 8 + 4];
    float o0 = a0.x * (v0.x - mu) * inv + b0.x;
    float o1 = a0.y * (v0.y - mu) * inv + b0.y;
    float o2 = a0.z * (v0.z - mu) * inv + b0.z;
    float o3 = a0.w * (v0.w - mu) * inv + b0.w;
    float o4 = a1.x * (v1.x - mu) * inv + b1.x;
    float o5 = a1.y * (v1.y - mu) * inv + b1.y;
    float o6 = a1.z * (v1.z - mu) * inv + b1.z;
    float o7 = a1.w * (v1.w - mu) * inv + b1.w;
    if (OB) {
        US8 o;
        o.u[0] = f2bf(o0); o.u[1] = f2bf(o1); o.u[2] = f2bf(o2); o.u[3] = f2bf(o3);
        o.u[4] = f2bf(o4); o.u[5] = f2bf(o5); o.u[6] = f2bf(o6); o.u[7] = f2bf(o7);
        *(US8*)((ushort*)yv + (long long)row * DD + lane * 8) = o;
    } else {
        float* yr = (float*)yv + (long long)row * DD + lane * 8;
        float4 w0 = {o0, o1, o2, o3}, w1 = {o4, o5, o6, o7};
        *(float4*)yr = w0;
        *(float4*)(yr + 4) = w1;
    }
}

// ---------------------------------------------------------------------------
__global__ __launch_bounds__(256) void softmax256_bf16_kernel(ushort* __restrict__ P)
{
    long long row = (long long)blockIdx.x * 4 + (threadIdx.x >> 6);
    int lane = threadIdx.x & 63;
    ushort* sr = P + row * 256 + lane * 4;
    ushort4 u = *(ushort4*)sr;
    float v0 = bf2f(u.x) * 0.125f, v1 = bf2f(u.y) * 0.125f,
          v2 = bf2f(u.z) * 0.125f, v3 = bf2f(u.w) * 0.125f;
    float m = fmaxf(fmaxf(v0, v1), fmaxf(v2, v3));
    #pragma unroll
    for (int off = 1; off < 64; off <<= 1) m = fmaxf(m, __shfl_xor(m, off, 64));
    v0 = __expf(v0 - m); v1 = __expf(v1 - m);
    v2 = __expf(v2 - m); v3 = __expf(v3 - m);
    float s = v0 + v1 + v2 + v3;
    #pragma unroll
    for (int off = 1; off < 64; off <<= 1) s += __shfl_xor(s, off, 64);
    float inv = 1.0f / s;
    u.x = f2bf(v0 * inv); u.y = f2bf(v1 * inv);
    u.z = f2bf(v2 * inv); u.w = f2bf(v3 * inv);
    *(ushort4*)sr = u;
}

// ---------------------------------------------------------------------------
__global__ __launch_bounds__(256) void wtrans_kernel(
    const float* __restrict__ src, ushort* __restrict__ dst,
    int Nsz, int Ksz, long long sSrc, long long sDst)
{
    __shared__ float tile[64][65];
    src += blockIdx.z * sSrc;
    dst += blockIdx.z * sDst;
    const int n0 = blockIdx.x * 64, k0 = blockIdx.y * 64;
    const int t = threadIdx.x, col = t & 63, r4 = t >> 6;
    #pragma unroll
    for (int p = 0; p < 16; ++p) {
        int row = p * 4 + r4;
        tile[row][col] = src[(long long)(k0 + row) * Nsz + n0 + col];
    }
    __syncthreads();
    #pragma unroll
    for (int p = 0; p < 16; ++p) {
        int row = p * 4 + r4;
        dst[(long long)(n0 + row) * Ksz + k0 + col] = f2bf(tile[col][row]);
    }
}

__global__ __launch_bounds__(256) void vtrans_kernel(
    const ushort* __restrict__ qkv, ushort* __restrict__ vT)
{
    __shared__ ushort tile[64][65];
    const int b = blockIdx.z;
    const int c0 = blockIdx.x * 64, a0 = blockIdx.y * 64;
    const int t = threadIdx.x, col = t & 63, r4 = t >> 6;
    const ushort* src = qkv + (long long)b * 256 * 1536 + 1024;
    ushort* dst = vT + (long long)b * 512 * 256;
    #pragma unroll
    for (int p = 0; p < 16; ++p) {
        int row = p * 4 + r4;
        tile[row][col] = src[(long long)(a0 + row) * 1536 + c0 + col];
    }
    __syncthreads();
    #pragma unroll
    for (int p = 0; p < 16; ++p) {
        int row = p * 4 + r4;
        dst[(long long)(c0 + row) * 256 + a0 + col] = tile[col][row];
    }
}

__global__ void concat_bias_kernel(const float* __restrict__ bq,
    const float* __restrict__ bk, const float* __restrict__ bv,
    float* __restrict__ o)
{
    int i = blockIdx.x * 256 + threadIdx.x;
    if (i >= NLAYER * 1536) return;
    int l = i / 1536, r = i % 1536;
    float v = r < 512 ? bq[l * 512 + r]
            : (r < 1024 ? bk[l * 512 + r - 512] : bv[l * 512 + r - 1024]);
    o[i] = v;
}

// ---------------------------------------------------------------------------
// WIDE GEMM: 256x128 tile, 512 threads = 8 waves (4m x 2n), wave tile 64x64
// (16 MFMA per K-32 step). 3 LDS buffers, 2 tiles in flight, counted vmcnt,
// ONE s_barrier per K-step (buffer written by stage(kt+2) is the one read at
// iter kt-1, whose reads completed before this iter's barrier). Both-side
// 16B-slot XOR swizzle. Optional split-K (kz) with fp32 atomicAdd epilogue
// directly into the residual trunk; bias added by kz==0 blocks only.
template<int NT, bool RELU, bool ATOM>
__global__ __launch_bounds__(512) void gemm_wide(
    const ushort* __restrict__ A, const ushort* __restrict__ B,
    const float* __restrict__ bias, void* __restrict__ Cv,
    int lda, int ldb, int ldc, int gn, int gm)
{
    constexpr int BK = 32;
    constexpr int S = 3;                 // gload16 issues per thread per tile
    __shared__ ushort As[3][256 * BK];
    __shared__ ushort Bs[3][128 * BK];

    const int t = threadIdx.x;
    const int nwg = gridDim.x, bid = blockIdx.x;
    const int swz = (bid & 7) * (nwg >> 3) + (bid >> 3);
    const int nb = swz % gn;
    const int mb = (swz / gn) % gm;
    const int kz = swz / (gn * gm);
    const int m0 = mb * 256, n0 = nb * 128;

    const int trow  = t >> 2;
    const int tslot = (t & 3) ^ ((t >> 3) & 3);
    const ushort* Ap = A + (long long)kz * (NT * 32)
                     + (long long)(m0 + trow) * lda + tslot * 8;
    const ushort* Bp = B + (long long)kz * (NT * 32)
                     + (long long)(n0 + trow) * ldb + tslot * 8;

    const int w = t >> 6, lane = t & 63;
    const int wr = w >> 1, wc = w & 1;          // 4 x 2 waves
    const int lr = lane & 15;
    const int slotK = (((lane >> 4) ^ ((lr >> 1) & 3)) * 8);

    f32x4_t acc[4][4];
    #pragma unroll
    for (int i = 0; i < 4; ++i)
        #pragma unroll
        for (int j = 0; j < 4; ++j)
            acc[i][j] = (f32x4_t){0.f, 0.f, 0.f, 0.f};

    auto stage = [&](int pf) {
        const int buf = pf % 3;
        const long long ko = (long long)pf * BK;
        gload16(Ap + ko,                          &As[buf][t * 8]);
        gload16(Ap + ko + (long long)128 * lda,   &As[buf][t * 8 + 4096]);
        gload16(Bp + ko,                          &Bs[buf][t * 8]);
    };

    auto kstep = [&](auto wn, int kt, int pf) {
        wait_vmcnt<decltype(wn)::value>();   // this wave's tile-kt loads done
        __builtin_amdgcn_sched_barrier(0);
        __builtin_amdgcn_s_barrier();        // all waves' tile-kt loads done
        __builtin_amdgcn_sched_barrier(0);
        if (pf >= 0) stage(pf);              // overwrites buf (kt-1): safe
        __builtin_amdgcn_sched_barrier(0);
        const int cb = kt % 3;
        bf16x8_t af[4], bfr[4];
        #pragma unroll
        for (int mf = 0; mf < 4; ++mf)
            af[mf] = *(const bf16x8_t*)&As[cb][(wr * 64 + mf * 16 + lr) * BK + slotK];
        #pragma unroll
        for (int nf = 0; nf < 4; ++nf)
            bfr[nf] = *(const bf16x8_t*)&Bs[cb][(wc * 64 + nf * 16 + lr) * BK + slotK];
        __builtin_amdgcn_s_setprio(1);
        #pragma unroll
        for (int mf = 0; mf < 4; ++mf)
            #pragma unroll
            for (int nf = 0; nf < 4; ++nf)
                acc[mf][nf] = __builtin_amdgcn_mfma_f32_16x16x32_bf16(
                    af[mf], bfr[nf], acc[mf][nf], 0, 0, 0);
        __builtin_amdgcn_s_setprio(0);
    };

    stage(0);
    stage(1);
    for (int kt = 0; kt < NT - 1; ++kt)
        kstep(ic<S>{}, kt, (kt + 2 < NT) ? (kt + 2) : -1);
    kstep(ic<0>{}, NT - 1, -1);

    #pragma unroll
    for (int nf = 0; nf < 4; ++nf) {
        const int col = n0 + wc * 64 + nf * 16 + lr;
        const float bv = (!ATOM || kz == 0) ? bias[col] : 0.0f;
        #pragma unroll
        for (int mf = 0; mf < 4; ++mf) {
            const int row0 = m0 + wr * 64 + mf * 16 + (lane >> 4) * 4;
            #pragma unroll
            for (int j = 0; j < 4; ++j) {
                float vv = acc[mf][nf][j] + bv;
                if (RELU) vv = fmaxf(vv, 0.0f);
                const long long idx = (long long)(row0 + j) * ldc + col;
                if (ATOM) unsafeAtomicAdd((float*)Cv + idx, vv);
                else      ((ushort*)Cv)[idx] = f2bf(vv);
            }
        }
    }
}

// ---------------------------------------------------------------------------
// Narrow GEMM (4 waves, 2x2) for the per-head attention GEMMs (QK^T, PV).
// Same single-barrier 3-buffer counted-vmcnt skeleton; bf16 out, no bias.
template<int BMt, int BNt, int NT>
__global__ __launch_bounds__(256) void gemm_np(
    const ushort* __restrict__ A, const ushort* __restrict__ B,
    ushort* __restrict__ C, int lda, int ldb, int ldc,
    int zdiv, long long sA1, long long sA2, long long sB1, long long sB2,
    long long sC1, long long sC2)
{
    constexpr int BK = 32;
    constexpr int AI = (BMt * BK) / 2048;
    constexpr int BI = (BNt * BK) / 2048;
    constexpr int S  = AI + BI;
    constexpr int HM = BMt / 2, HN = BNt / 2;
    constexpr int RM = HM / 16, RN = HN / 16;

    __shared__ ushort As[3][BMt * BK];
    __shared__ ushort Bs[3][BNt * BK];

    const int t = threadIdx.x;
    const int z = blockIdx.z;
    const int zq = z / zdiv, zr = z % zdiv;
    const int m0 = blockIdx.y * BMt, n0 = blockIdx.x * BNt;

    const int trow  = t >> 2;
    const int tslot = (t & 3) ^ ((t >> 3) & 3);
    const ushort* Ap = A + zq * sA1 + zr * sA2
                     + (long long)(m0 + trow) * lda + tslot * 8;
    const ushort* Bp = B + zq * sB1 + zr * sB2
                     + (long long)(n0 + trow) * ldb + tslot * 8;

    const int w = t >> 6, lane = t & 63;
    const int wr = w >> 1, wc = w & 1;
    const int lr = lane & 15;
    const int slotK = (((lane >> 4) ^ ((lr >> 1) & 3)) * 8);

    f32x4_t acc[RM][RN];
    #pragma unroll
    for (int i = 0; i < RM; ++i)
        #pragma unroll
        for (int j = 0; j < RN; ++j)
            acc[i][j] = (f32x4_t){0.f, 0.f, 0.f, 0.f};

    auto stage = [&](int pf) {
        const int buf = pf % 3;
        const long long ko = (long long)pf * BK;
        #pragma unroll
        for (int i = 0; i < AI; ++i)
            gload16(Ap + ko + (long long)i * 64 * lda, &As[buf][t * 8 + i * 2048]);
        #pragma unroll
        for (int i = 0; i < BI; ++i)
            gload16(Bp + ko + (long long)i * 64 * ldb, &Bs[buf][t * 8 + i * 2048]);
    };

    auto kstep = [&](auto wn, int kt, int pf) {
        wait_vmcnt<decltype(wn)::value>();
        __builtin_amdgcn_sched_barrier(0);
        __builtin_amdgcn_s_barrier();
        __builtin_amdgcn_sched_barrier(0);
        if (pf >= 0) stage(pf);
        __builtin_amdgcn_sched_barrier(0);
        const int cb = kt % 3;
        bf16x8_t af[RM], bfr[RN];
        #pragma unroll
        for (int mf = 0; mf < RM; ++mf)
            af[mf] = *(const bf16x8_t*)&As[cb][(wr * HM + mf * 16 + lr) * BK + slotK];
        #pragma unroll
        for (int nf = 0; nf < RN; ++nf)
            bfr[nf] = *(const bf16x8_t*)&Bs[cb][(wc * HN + nf * 16 + lr) * BK + slotK];
        __builtin_amdgcn_s_setprio(1);
        #pragma unroll
        for (int mf = 0; mf < RM; ++mf)
            #pragma unroll
            for (int nf = 0; nf < RN; ++nf)
                acc[mf][nf] = __builtin_amdgcn_mfma_f32_16x16x32_bf16(
                    af[mf], bfr[nf], acc[mf][nf], 0, 0, 0);
        __builtin_amdgcn_s_setprio(0);
    };

    stage(0);
    if constexpr (NT >= 2) stage(1);
    for (int kt = 0; kt < NT - 1; ++kt)
        kstep(ic<S>{}, kt, (kt + 2 < NT) ? (kt + 2) : -1);
    kstep(ic<0>{}, NT - 1, -1);

    const long long coff = zq * sC1 + zr * sC2;
    #pragma unroll
    for (int nf = 0; nf < RN; ++nf) {
        const int col = n0 + wc * HN + nf * 16 + lr;
        #pragma unroll
        for (int mf = 0; mf < RM; ++mf) {
            const int row0 = m0 + wr * HM + mf * 16 + (lane >> 4) * 4;
            #pragma unroll
            for (int j = 0; j < 4; ++j)
                C[coff + (long long)(row0 + j) * ldc + col] = f2bf(acc[mf][nf][j]);
        }
    }
}

// ---------------------------------------------------------------------------
__global__ __launch_bounds__(256) void edge_heads_kernel(
    const float* __restrict__ h, const float* __restrict__ Wfl,
    float* __restrict__ L, float* __restrict__ R)
{
    int row = blockIdx.x * 4 + (threadIdx.x >> 6);
    int lane = threadIdx.x & 63;
    const float* hr = h + (long long)row * DD;
    float accL[NB] = {}, accR[NB] = {};
    #pragma unroll
    for (int tt = 0; tt < 8; ++tt) {
        int e = lane * 8 + tt;
        float hv = hr[e];
        #pragma unroll
        for (int n = 0; n < NB; ++n) {
            accL[n] = fmaf(hv, Wfl[e * NB + n], accL[n]);
            accR[n] = fmaf(hv, Wfl[(DD + e) * NB + n], accR[n]);
        }
    }
    #pragma unroll
    for (int n = 0; n < NB; ++n) {
        #pragma unroll
        for (int off = 1; off < 64; off <<= 1) {
            accL[n] += __shfl_xor(accL[n], off, 64);
            accR[n] += __shfl_xor(accR[n], off, 64);
        }
    }
    if (lane == 0) {
        #pragma unroll
        for (int n = 0; n < NB; ++n) {
            L[row * NB + n] = accL[n];
            R[row * NB + n] = accR[n];
        }
    }
}

__global__ __launch_bounds__(256) void edge_combine_kernel(
    const float* __restrict__ L, const float* __restrict__ R,
    const float* __restrict__ bfl, float* __restrict__ out)
{
    int idx = blockIdx.x * 256 + threadIdx.x;
    int j = idx & 255;
    int bi = idx >> 8;
    int b = bi >> 8;
    float4 l = *(const float4*)&L[bi * NB];
    float4 r = *(const float4*)&R[(b * 256 + j) * NB];
    float4 bf = *(const float4*)bfl;
    float4 o;
    o.x = l.x + r.x + bf.x; o.y = l.y + r.y + bf.y;
    o.z = l.z + r.z + bf.z; o.w = l.w + r.w + bf.w;
    *(float4*)&out[(long long)idx * NB] = o;
}

// ---------------------------------------------------------------------------
extern "C" void kernel_launch(void* const* d_in, const int* in_sizes, int n_in,
                              void* d_out, int out_size, void* d_ws, size_t ws_size,
                              hipStream_t stream)
{
    const int*   src   = (const int*)  d_in[0];
    const float* pe    = (const float*)d_in[3];
    const float* emb   = (const float*)d_in[4];
    const float* Wq    = (const float*)d_in[5];
    const float* Wk    = (const float*)d_in[6];
    const float* Wv    = (const float*)d_in[7];
    const float* Wo    = (const float*)d_in[8];
    const float* W1    = (const float*)d_in[9];
    const float* W2    = (const float*)d_in[10];
    const float* Wfl   = (const float*)d_in[11];
    const float* bq    = (const float*)d_in[12];
    const float* bk    = (const float*)d_in[13];
    const float* bv    = (const float*)d_in[14];
    const float* bo    = (const float*)d_in[15];
    const float* b1    = (const float*)d_in[16];
    const float* b2    = (const float*)d_in[17];
    const float* ln1_b = (const float*)d_in[18];
    const float* ln2_b = (const float*)d_in[19];
    const float* fn_b  = (const float*)d_in[20];
    const float* bfl   = (const float*)d_in[21];
    const float* ln1_a = (const float*)d_in[22];
    const float* ln2_a = (const float*)d_in[23];
    const float* fn_a  = (const float*)d_in[24];
    float* out = (float*)d_out;

    const long long ROWS = (long long)BB * AA;   // 8192
    char* p = (char*)d_ws;
    float*  x    = (float*)p;  p += ROWS * DD * 4;            // 16 MB
    ushort* x2b  = (ushort*)p; p += ROWS * DD * 2;            // 8 MB (aliased by attn-out o)
    ushort* qkv  = (ushort*)p;                                 // 24 MB
    ushort* h1   = qkv;                                        // aliases qkv+vT (32 MB)
    p += ROWS * 1536 * 2;
    ushort* vT   = (ushort*)p; p += (long long)BB * DD * AA * 2;   // 8 MB
    ushort* P    = (ushort*)p; p += (long long)BB * HH * AA * AA * 2; // 32 MB
    ushort* Wqkvt= (ushort*)p; p += (long long)NLAYER * 1536 * 512 * 2;
    ushort* Wot  = (ushort*)p; p += (long long)NLAYER * 512 * 512 * 2;
    ushort* W1t  = (ushort*)p; p += (long long)NLAYER * 2048 * 512 * 2;
    ushort* W2t  = (ushort*)p; p += (long long)NLAYER * 512 * 2048 * 2;
    float*  bqkv = (float*)p;  p += (long long)NLAYER * 1536 * 4;
    float*  left = (float*)p;  p += ROWS * NB * 4;
    float*  right= (float*)p;  p += ROWS * NB * 4;

    // ---- weight prep (bf16, K-major) ----
    wtrans_kernel<<<dim3(8, 8, 6),  256, 0, stream>>>(Wq, Wqkvt,          512,  512,  262144LL,  786432LL);
    wtrans_kernel<<<dim3(8, 8, 6),  256, 0, stream>>>(Wk, Wqkvt + 262144, 512,  512,  262144LL,  786432LL);
    wtrans_kernel<<<dim3(8, 8, 6),  256, 0, stream>>>(Wv, Wqkvt + 524288, 512,  512,  262144LL,  786432LL);
    wtrans_kernel<<<dim3(8, 8, 6),  256, 0, stream>>>(Wo, Wot,            512,  512,  262144LL,  262144LL);
    wtrans_kernel<<<dim3(32, 8, 6), 256, 0, stream>>>(W1, W1t,            2048, 512,  1048576LL, 1048576LL);
    wtrans_kernel<<<dim3(8, 32, 6), 256, 0, stream>>>(W2, W2t,            512,  2048, 1048576LL, 1048576LL);
    concat_bias_kernel<<<36, 256, 0, stream>>>(bq, bk, bv, bqkv);

    // ---- embed + PE ----
    embed_pe_kernel<<<4096, 256, 0, stream>>>(src, emb, pe, x);

    for (int i = 0; i < NLAYER; ++i) {
        // LN1 -> bf16
        layernorm512_kernel<true><<<2048, 256, 0, stream>>>(
            x, ln1_a + i * DD, ln1_b + i * DD, x2b);
        // fused QKV projection: [8192x1536], K=512, grid 12*32=384
        gemm_wide<16, false, false><<<384, 512, 0, stream>>>(
            x2b, Wqkvt + (long long)i * 786432, bqkv + i * 1536, qkv,
            512, 512, 1536, 12, 32);
        // V head-transpose
        vtrans_kernel<<<dim3(8, 4, 32), 256, 0, stream>>>(qkv, vT);
        // S = Q@K^T (scale folded into softmax), K=64 (NT=2)
        gemm_np<128, 128, 2><<<dim3(2, 2, 256), 256, 0, stream>>>(
            qkv, qkv + 512, P, 1536, 1536, 256, HH,
            393216LL, 64LL, 393216LL, 64LL, 524288LL, 65536LL);
        // softmax (x0.125), in-place bf16
        softmax256_bf16_kernel<<<16384, 256, 0, stream>>>(P);
        // O = P@V, K=256 (NT=8)
        gemm_np<128, 64, 8><<<dim3(1, 2, 256), 256, 0, stream>>>(
            P, vT, x2b, 256, 256, 512, HH,
            524288LL, 65536LL, 131072LL, 16384LL, 131072LL, 64LL);
        // x += O@Wo + bo : split-K=2, fp32 atomics into x, grid 4*32*2=256
        gemm_wide<8, false, true><<<256, 512, 0, stream>>>(
            x2b, Wot + (long long)i * 262144, bo + i * DD, x,
            512, 512, 512, 4, 32);
        // LN2 -> bf16
        layernorm512_kernel<true><<<2048, 256, 0, stream>>>(
            x, ln2_a + i * DD, ln2_b + i * DD, x2b);
        // h1 = relu(x2@W1 + b1), K=512, grid 16*32=512
        gemm_wide<16, true, false><<<512, 512, 0, stream>>>(
            x2b, W1t + (long long)i * 1048576, b1 + i * DFF, h1,
            512, 512, 2048, 16, 32);
        // x += h1@W2 + b2 : split-K=2 (K=1024 each), atomics, grid 4*32*2=256
        gemm_wide<32, false, true><<<256, 512, 0, stream>>>(
            h1, W2t + (long long)i * 1048576, b2 + i * DD, x,
            2048, 2048, 512, 4, 32);
    }

    // final norm (fp32, in place), edge heads + combine
    layernorm512_kernel<false><<<2048, 256, 0, stream>>>(x, fn_a, fn_b, x);
    edge_heads_kernel<<<2048, 256, 0, stream>>>(x, Wfl, left, right);
    edge_combine_kernel<<<8192, 256, 0, stream>>>(left, right, bfl, out);
}

// Round 6
// 842.729 us; speedup vs baseline: 1.3689x; 1.3689x over previous
//
#include <hip/hip_runtime.h>
#include <hip/hip_bf16.h>
#include <type_traits>

#define BB 32
#define AA 256
#define DD 512
#define HH 8
#define NLAYER 6
#define DFF 2048
#define NB 4

typedef float  f32x4_t  __attribute__((ext_vector_type(4)));
typedef short  bf16x8_t __attribute__((ext_vector_type(8)));

struct __align__(16) US8 { ushort u[8]; };

__device__ __forceinline__ ushort f2bf(float f) {
    __hip_bfloat16 h = __float2bfloat16(f);
    return *reinterpret_cast<ushort*>(&h);
}
__device__ __forceinline__ float bf2f(ushort u) {
    __hip_bfloat16 h;
    *reinterpret_cast<ushort*>(&h) = u;
    return __bfloat162float(h);
}

// async global->LDS, 16B per lane (dest linear: wave base + lane*16)
__device__ __forceinline__ void gload16(const void* g, void* l) {
    __builtin_amdgcn_global_load_lds(
        (const __attribute__((address_space(1))) void*)g,
        (__attribute__((address_space(3))) void*)l, 16, 0, 0);
}

template<int N> __device__ __forceinline__ void wait_vmcnt() {
    if constexpr      (N == 0)  asm volatile("s_waitcnt vmcnt(0)"  ::: "memory");
    else if constexpr (N == 3)  asm volatile("s_waitcnt vmcnt(3)"  ::: "memory");
    else if constexpr (N == 4)  asm volatile("s_waitcnt vmcnt(4)"  ::: "memory");
    else static_assert(N == 0, "add vmcnt literal");
}
template<int N> using ic = std::integral_constant<int, N>;

// ---------------------------------------------------------------------------
__global__ __launch_bounds__(256) void embed_pe_kernel(
    const int* __restrict__ src, const float* __restrict__ embed,
    const float* __restrict__ pe, float* __restrict__ x)
{
    int t = blockIdx.x * 256 + threadIdx.x;
    int d4 = t & 127;
    int row = t >> 7;
    int a = row & 255;
    int d = d4 * 4;
    int sub = d >> 6;
    int e = d & 63;
    int tok = src[row * 8 + sub];
    float4 em = *(const float4*)&embed[tok * 64 + e];
    float4 p  = *(const float4*)&pe[a * DD + d];
    const float s = 22.627416997969522f;  // sqrt(512)
    float4 r;
    r.x = em.x * s + p.x; r.y = em.y * s + p.y;
    r.z = em.z * s + p.z; r.w = em.w * s + p.w;
    *(float4*)&x[(long long)row * DD + d] = r;
}

// ---------------------------------------------------------------------------
template<bool OB>
__global__ __launch_bounds__(256) void layernorm512_kernel(
    const float* x, const float* __restrict__ alpha,
    const float* __restrict__ beta, void* yv)
{
    const int row = blockIdx.x * 4 + (threadIdx.x >> 6);
    const int lane = threadIdx.x & 63;
    const float* xr = x + (long long)row * DD;
    float4 v0 = *(const float4*)&xr[lane * 8];
    float4 v1 = *(const float4*)&xr[lane * 8 + 4];
    float s  = v0.x + v0.y + v0.z + v0.w + v1.x + v1.y + v1.z + v1.w;
    float ss = v0.x*v0.x + v0.y*v0.y + v0.z*v0.z + v0.w*v0.w
             + v1.x*v1.x + v1.y*v1.y + v1.z*v1.z + v1.w*v1.w;
    #pragma unroll
    for (int off = 1; off < 64; off <<= 1) {
        s  += __shfl_xor(s, off, 64);
        ss += __shfl_xor(ss, off, 64);
    }
    float mu = s * (1.0f / 512.0f);
    float var = fmaxf(ss - 512.0f * mu * mu, 0.0f) * (1.0f / 511.0f);
    float inv = 1.0f / (sqrtf(var) + 1e-6f);
    float4 a0 = *(const float4*)&alpha[lane * 8];
    float4 a1 = *(const float4*)&alpha[lane * 8 + 4];
    float4 b0 = *(const float4*)&beta[lane * 8];
    float4 b1 = *(const float4*)&beta[lane * 8 + 4];
    float o0 = a0.x * (v0.x - mu) * inv + b0.x;
    float o1 = a0.y * (v0.y - mu) * inv + b0.y;
    float o2 = a0.z * (v0.z - mu) * inv + b0.z;
    float o3 = a0.w * (v0.w - mu) * inv + b0.w;
    float o4 = a1.x * (v1.x - mu) * inv + b1.x;
    float o5 = a1.y * (v1.y - mu) * inv + b1.y;
    float o6 = a1.z * (v1.z - mu) * inv + b1.z;
    float o7 = a1.w * (v1.w - mu) * inv + b1.w;
    if (OB) {
        US8 o;
        o.u[0] = f2bf(o0); o.u[1] = f2bf(o1); o.u[2] = f2bf(o2); o.u[3] = f2bf(o3);
        o.u[4] = f2bf(o4); o.u[5] = f2bf(o5); o.u[6] = f2bf(o6); o.u[7] = f2bf(o7);
        *(US8*)((ushort*)yv + (long long)row * DD + lane * 8) = o;
    } else {
        float* yr = (float*)yv + (long long)row * DD + lane * 8;
        float4 w0 = {o0, o1, o2, o3}, w1 = {o4, o5, o6, o7};
        *(float4*)yr = w0;
        *(float4*)(yr + 4) = w1;
    }
}

// ---------------------------------------------------------------------------
__global__ __launch_bounds__(256) void wtrans_kernel(
    const float* __restrict__ src, ushort* __restrict__ dst,
    int Nsz, int Ksz, long long sSrc, long long sDst)
{
    __shared__ float tile[64][65];
    src += blockIdx.z * sSrc;
    dst += blockIdx.z * sDst;
    const int n0 = blockIdx.x * 64, k0 = blockIdx.y * 64;
    const int t = threadIdx.x, col = t & 63, r4 = t >> 6;
    #pragma unroll
    for (int p = 0; p < 16; ++p) {
        int row = p * 4 + r4;
        tile[row][col] = src[(long long)(k0 + row) * Nsz + n0 + col];
    }
    __syncthreads();
    #pragma unroll
    for (int p = 0; p < 16; ++p) {
        int row = p * 4 + r4;
        dst[(long long)(n0 + row) * Ksz + k0 + col] = f2bf(tile[col][row]);
    }
}

__global__ __launch_bounds__(256) void vtrans_kernel(
    const ushort* __restrict__ qkv, ushort* __restrict__ vT)
{
    __shared__ ushort tile[64][65];
    const int b = blockIdx.z;
    const int c0 = blockIdx.x * 64, a0 = blockIdx.y * 64;
    const int t = threadIdx.x, col = t & 63, r4 = t >> 6;
    const ushort* src = qkv + (long long)b * 256 * 1536 + 1024;
    ushort* dst = vT + (long long)b * 512 * 256;
    #pragma unroll
    for (int p = 0; p < 16; ++p) {
        int row = p * 4 + r4;
        tile[row][col] = src[(long long)(a0 + row) * 1536 + c0 + col];
    }
    __syncthreads();
    #pragma unroll
    for (int p = 0; p < 16; ++p) {
        int row = p * 4 + r4;
        dst[(long long)(c0 + row) * 256 + a0 + col] = tile[col][row];
    }
}

__global__ void concat_bias_kernel(const float* __restrict__ bq,
    const float* __restrict__ bk, const float* __restrict__ bv,
    float* __restrict__ o)
{
    int i = blockIdx.x * 256 + threadIdx.x;
    if (i >= NLAYER * 1536) return;
    int l = i / 1536, r = i % 1536;
    float v = r < 512 ? bq[l * 512 + r]
            : (r < 1024 ? bk[l * 512 + r - 512] : bv[l * 512 + r - 1024]);
    o[i] = v;
}

// ---------------------------------------------------------------------------
// Fused attention: one block per (b,h). 8 waves, 2 passes x 16 q-rows/wave.
// K[256x64] and V^T[64x256] staged once in LDS (pre-swizzled source, XOR'd
// reads). S^T computed as mfma(K,Q) so each lane owns a full softmax row:
// lane (lg,lr) holds S[j = jf*16+lg*4+r][i = i0+lr]. P goes to wave-private
// LDS (bank-swizzled), then PV = mfma(P, V^T). No inter-wave barriers after
// the initial stage.
__global__ __launch_bounds__(512, 1) void attn_kernel(
    const ushort* __restrict__ qkv, const ushort* __restrict__ vT,
    ushort* __restrict__ Ob)
{
    __shared__ ushort Kl[256 * 64];       // 32 KB  [j][k]
    __shared__ ushort Vl[64 * 256];       // 32 KB  [c][j]
    __shared__ ushort Pl[8 * 16 * 256];   // 64 KB  per-wave [i][j]

    const int t = threadIdx.x;
    const int bh = blockIdx.x;
    const int b = bh >> 3, h = bh & 7;
    const int w = t >> 6, lane = t & 63;
    const int lr = lane & 15, lg = lane >> 4;

    {   // stage K and V^T (pre-swizzled global source, linear LDS dest)
        const int j = t >> 3, slot = t & 7;
        const int chunk = slot ^ (j & 7);
        const ushort* srcK = qkv + (long long)(b * 256 + j) * 1536 + 512 + h * 64 + chunk * 8;
        const int c = t >> 5, slv = t & 31;
        const int chv = slv ^ (c & 7);
        const ushort* srcV = vT + (long long)b * 131072 + (long long)(h * 64 + c) * 256 + chv * 8;
        #pragma unroll
        for (int r = 0; r < 4; ++r) {
            gload16(srcK + (long long)r * 64 * 1536, &Kl[(t + r * 512) * 8]);
            gload16(srcV + (long long)r * 16 * 256,  &Vl[(t + r * 512) * 8]);
        }
    }
    asm volatile("s_waitcnt vmcnt(0)" ::: "memory");
    __builtin_amdgcn_sched_barrier(0);
    __builtin_amdgcn_s_barrier();
    __builtin_amdgcn_sched_barrier(0);

    char* Pw = (char*)Pl + w * 8192;
    const char* Kc = (const char*)Kl;
    const char* Vc = (const char*)Vl;

    #pragma unroll 1
    for (int pass = 0; pass < 2; ++pass) {
        const int i0 = pass * 128 + w * 16;
        // Q fragments straight from global (B-operand: lane lr -> row i0+lr)
        const ushort* qbase = qkv + (long long)(b * 256 + i0 + lr) * 1536 + h * 64 + lg * 8;
        bf16x8_t qf0 = *(const bf16x8_t*)qbase;
        bf16x8_t qf1 = *(const bf16x8_t*)(qbase + 32);

        // S^T = K @ Q^T  (j at (lg*4+r)+16*jf, i at lr)
        f32x4_t s[16];
        #pragma unroll
        for (int jf = 0; jf < 16; ++jf) s[jf] = (f32x4_t){0.f, 0.f, 0.f, 0.f};
        #pragma unroll
        for (int jf = 0; jf < 16; ++jf) {
            const int row = jf * 16 + lr;
            bf16x8_t k0 = *(const bf16x8_t*)(Kc + row * 128 + ((lg ^ (row & 7)) * 16));
            s[jf] = __builtin_amdgcn_mfma_f32_16x16x32_bf16(k0, qf0, s[jf], 0, 0, 0);
        }
        #pragma unroll
        for (int jf = 0; jf < 16; ++jf) {
            const int row = jf * 16 + lr;
            bf16x8_t k1 = *(const bf16x8_t*)(Kc + row * 128 + (((4 + lg) ^ (row & 7)) * 16));
            s[jf] = __builtin_amdgcn_mfma_f32_16x16x32_bf16(k1, qf1, s[jf], 0, 0, 0);
        }

        // softmax over all 256 j for this lane's i (in-lane 64 + 2 shfl)
        float m = -3.0e38f;
        #pragma unroll
        for (int jf = 0; jf < 16; ++jf)
            #pragma unroll
            for (int r = 0; r < 4; ++r) m = fmaxf(m, s[jf][r]);
        m = fmaxf(m, __shfl_xor(m, 16, 64));
        m = fmaxf(m, __shfl_xor(m, 32, 64));
        float l = 0.f;
        #pragma unroll
        for (int jf = 0; jf < 16; ++jf)
            #pragma unroll
            for (int r = 0; r < 4; ++r) {
                float e = __expf((s[jf][r] - m) * 0.125f);
                s[jf][r] = e; l += e;
            }
        l += __shfl_xor(l, 16, 64);
        l += __shfl_xor(l, 32, 64);
        const float inv = 1.0f / l;

        // P -> wave-private LDS, bank-swizzled (byte ^= (i&7)<<4)
        #pragma unroll
        for (int jf = 0; jf < 16; ++jf) {
            ushort4 u;
            u.x = f2bf(s[jf][0] * inv); u.y = f2bf(s[jf][1] * inv);
            u.z = f2bf(s[jf][2] * inv); u.w = f2bf(s[jf][3] * inv);
            const int off = (lr * 512 + jf * 32 + lg * 8) ^ ((lr & 7) << 4);
            *(ushort4*)(Pw + off) = u;
        }
        asm volatile("s_waitcnt lgkmcnt(0)" ::: "memory");   // rule #18
        __builtin_amdgcn_sched_barrier(0);

        // O = P @ V^T : A = P rows i (lr), B = V^T rows c (lr)
        f32x4_t o[4];
        #pragma unroll
        for (int cf = 0; cf < 4; ++cf) o[cf] = (f32x4_t){0.f, 0.f, 0.f, 0.f};
        #pragma unroll
        for (int ks = 0; ks < 8; ++ks) {
            bf16x8_t pa = *(const bf16x8_t*)(Pw +
                ((lr * 512 + ks * 64 + lg * 16) ^ ((lr & 7) << 4)));
            #pragma unroll
            for (int cf = 0; cf < 4; ++cf) {
                const int crow = cf * 16 + lr;
                bf16x8_t vb = *(const bf16x8_t*)(Vc + crow * 512 +
                    (((ks * 4 + lg) ^ (crow & 7)) * 16));
                o[cf] = __builtin_amdgcn_mfma_f32_16x16x32_bf16(pa, vb, o[cf], 0, 0, 0);
            }
        }
        asm volatile("s_waitcnt lgkmcnt(0)" ::: "memory");   // P reads done before next pass
        __builtin_amdgcn_sched_barrier(0);

        #pragma unroll
        for (int cf = 0; cf < 4; ++cf) {
            const int c = cf * 16 + lr;
            #pragma unroll
            for (int r = 0; r < 4; ++r) {
                const int i = i0 + lg * 4 + r;
                Ob[(long long)(b * 256 + i) * 512 + h * 64 + c] = f2bf(o[cf][r]);
            }
        }
    }
}

// ---------------------------------------------------------------------------
// WIDE GEMM: 256x128 tile, 512 threads = 8 waves (4x2), wave tile 64x64.
// 3 LDS buffers, 2 tiles in flight, counted vmcnt, one barrier per K-step.
// bf16 out + bias (+relu). XCD-chunked 1-D swizzled grid (multiple of 8).
template<int NT, bool RELU>
__global__ __launch_bounds__(512) void gemm_wide(
    const ushort* __restrict__ A, const ushort* __restrict__ B,
    const float* __restrict__ bias, ushort* __restrict__ C,
    int lda, int ldb, int ldc, int gn)
{
    constexpr int BK = 32;
    constexpr int S = 3;
    __shared__ ushort As[3][256 * BK];
    __shared__ ushort Bs[3][128 * BK];

    const int t = threadIdx.x;
    const int nwg = gridDim.x, bid = blockIdx.x;
    const int swz = (bid & 7) * (nwg >> 3) + (bid >> 3);
    const int nb = swz % gn;
    const int mb = swz / gn;
    const int m0 = mb * 256, n0 = nb * 128;

    const int trow  = t >> 2;
    const int tslot = (t & 3) ^ ((t >> 3) & 3);
    const ushort* Ap = A + (long long)(m0 + trow) * lda + tslot * 8;
    const ushort* Bp = B + (long long)(n0 + trow) * ldb + tslot * 8;

    const int w = t >> 6, lane = t & 63;
    const int wr = w >> 1, wc = w & 1;
    const int lr = lane & 15;
    const int slotK = (((lane >> 4) ^ ((lr >> 1) & 3)) * 8);

    f32x4_t acc[4][4];
    #pragma unroll
    for (int i = 0; i < 4; ++i)
        #pragma unroll
        for (int j = 0; j < 4; ++j)
            acc[i][j] = (f32x4_t){0.f, 0.f, 0.f, 0.f};

    auto stage = [&](int pf) {
        const int buf = pf % 3;
        const long long ko = (long long)pf * BK;
        gload16(Ap + ko,                        &As[buf][t * 8]);
        gload16(Ap + ko + (long long)128 * lda, &As[buf][t * 8 + 4096]);
        gload16(Bp + ko,                        &Bs[buf][t * 8]);
    };

    auto kstep = [&](auto wn, int kt, int pf) {
        wait_vmcnt<decltype(wn)::value>();
        __builtin_amdgcn_sched_barrier(0);
        __builtin_amdgcn_s_barrier();
        __builtin_amdgcn_sched_barrier(0);
        if (pf >= 0) stage(pf);
        __builtin_amdgcn_sched_barrier(0);
        const int cb = kt % 3;
        bf16x8_t af[4], bfr[4];
        #pragma unroll
        for (int mf = 0; mf < 4; ++mf)
            af[mf] = *(const bf16x8_t*)&As[cb][(wr * 64 + mf * 16 + lr) * BK + slotK];
        #pragma unroll
        for (int nf = 0; nf < 4; ++nf)
            bfr[nf] = *(const bf16x8_t*)&Bs[cb][(wc * 64 + nf * 16 + lr) * BK + slotK];
        __builtin_amdgcn_s_setprio(1);
        #pragma unroll
        for (int mf = 0; mf < 4; ++mf)
            #pragma unroll
            for (int nf = 0; nf < 4; ++nf)
                acc[mf][nf] = __builtin_amdgcn_mfma_f32_16x16x32_bf16(
                    af[mf], bfr[nf], acc[mf][nf], 0, 0, 0);
        __builtin_amdgcn_s_setprio(0);
    };

    stage(0);
    stage(1);
    for (int kt = 0; kt < NT - 1; ++kt)
        kstep(ic<S>{}, kt, (kt + 2 < NT) ? (kt + 2) : -1);
    kstep(ic<0>{}, NT - 1, -1);

    #pragma unroll
    for (int nf = 0; nf < 4; ++nf) {
        const int col = n0 + wc * 64 + nf * 16 + lr;
        const float bv = bias[col];
        #pragma unroll
        for (int mf = 0; mf < 4; ++mf) {
            const int row0 = m0 + wr * 64 + mf * 16 + (lane >> 4) * 4;
            #pragma unroll
            for (int j = 0; j < 4; ++j) {
                float vv = acc[mf][nf][j] + bv;
                if (RELU) vv = fmaxf(vv, 0.0f);
                C[(long long)(row0 + j) * ldc + col] = f2bf(vv);
            }
        }
    }
}

// ---------------------------------------------------------------------------
// Narrow GEMM (4 waves, 2x2), 3-buffer counted-vmcnt skeleton, full epilogue
// (bias, relu, fp32 residual or bf16 out). SWZ: 1-D XCD-chunked grid.
template<int BMt, int BNt, int NT, bool OBF16, bool RELU, bool RES, bool SWZ>
__global__ __launch_bounds__(256) void gemm_nar(
    const ushort* __restrict__ A, const ushort* __restrict__ B,
    const float* __restrict__ bias, const float* __restrict__ res,
    void* __restrict__ Cv, int lda, int ldb, int ldc, int gx,
    int zdiv, long long sA1, long long sA2, long long sB1, long long sB2,
    long long sC1, long long sC2)
{
    constexpr int BK = 32;
    constexpr int AI = (BMt * BK) / 2048;
    constexpr int BI = (BNt * BK) / 2048;
    constexpr int S  = AI + BI;
    constexpr int HM = BMt / 2, HN = BNt / 2;
    constexpr int RM = HM / 16, RN = HN / 16;

    __shared__ ushort As[3][BMt * BK];
    __shared__ ushort Bs[3][BNt * BK];

    const int t = threadIdx.x;
    int nb, mb, zq, zr;
    if (SWZ) {
        const int nwg = gridDim.x, bid = blockIdx.x;
        const int swz = (bid & 7) * (nwg >> 3) + (bid >> 3);
        nb = swz % gx; mb = swz / gx; zq = 0; zr = 0;
    } else {
        nb = blockIdx.x; mb = blockIdx.y;
        const int z = blockIdx.z;
        zq = z / zdiv; zr = z % zdiv;
    }
    const int m0 = mb * BMt, n0 = nb * BNt;

    const int trow  = t >> 2;
    const int tslot = (t & 3) ^ ((t >> 3) & 3);
    const ushort* Ap = A + zq * sA1 + zr * sA2
                     + (long long)(m0 + trow) * lda + tslot * 8;
    const ushort* Bp = B + zq * sB1 + zr * sB2
                     + (long long)(n0 + trow) * ldb + tslot * 8;

    const int w = t >> 6, lane = t & 63;
    const int wr = w >> 1, wc = w & 1;
    const int lr = lane & 15;
    const int slotK = (((lane >> 4) ^ ((lr >> 1) & 3)) * 8);

    f32x4_t acc[RM][RN];
    #pragma unroll
    for (int i = 0; i < RM; ++i)
        #pragma unroll
        for (int j = 0; j < RN; ++j)
            acc[i][j] = (f32x4_t){0.f, 0.f, 0.f, 0.f};

    auto stage = [&](int pf) {
        const int buf = pf % 3;
        const long long ko = (long long)pf * BK;
        #pragma unroll
        for (int i = 0; i < AI; ++i)
            gload16(Ap + ko + (long long)i * 64 * lda, &As[buf][t * 8 + i * 2048]);
        #pragma unroll
        for (int i = 0; i < BI; ++i)
            gload16(Bp + ko + (long long)i * 64 * ldb, &Bs[buf][t * 8 + i * 2048]);
    };

    auto kstep = [&](auto wn, int kt, int pf) {
        wait_vmcnt<decltype(wn)::value>();
        __builtin_amdgcn_sched_barrier(0);
        __builtin_amdgcn_s_barrier();
        __builtin_amdgcn_sched_barrier(0);
        if (pf >= 0) stage(pf);
        __builtin_amdgcn_sched_barrier(0);
        const int cb = kt % 3;
        bf16x8_t af[RM], bfr[RN];
        #pragma unroll
        for (int mf = 0; mf < RM; ++mf)
            af[mf] = *(const bf16x8_t*)&As[cb][(wr * HM + mf * 16 + lr) * BK + slotK];
        #pragma unroll
        for (int nf = 0; nf < RN; ++nf)
            bfr[nf] = *(const bf16x8_t*)&Bs[cb][(wc * HN + nf * 16 + lr) * BK + slotK];
        __builtin_amdgcn_s_setprio(1);
        #pragma unroll
        for (int mf = 0; mf < RM; ++mf)
            #pragma unroll
            for (int nf = 0; nf < RN; ++nf)
                acc[mf][nf] = __builtin_amdgcn_mfma_f32_16x16x32_bf16(
                    af[mf], bfr[nf], acc[mf][nf], 0, 0, 0);
        __builtin_amdgcn_s_setprio(0);
    };

    stage(0);
    if constexpr (NT >= 2) stage(1);
    for (int kt = 0; kt < NT - 1; ++kt)
        kstep(ic<S>{}, kt, (kt + 2 < NT) ? (kt + 2) : -1);
    kstep(ic<0>{}, NT - 1, -1);

    const long long coff = zq * sC1 + zr * sC2;
    #pragma unroll
    for (int nf = 0; nf < RN; ++nf) {
        const int col = n0 + wc * HN + nf * 16 + lr;
        const float bv = bias ? bias[col] : 0.0f;
        #pragma unroll
        for (int mf = 0; mf < RM; ++mf) {
            const int row0 = m0 + wr * HM + mf * 16 + (lane >> 4) * 4;
            #pragma unroll
            for (int j = 0; j < 4; ++j) {
                float vv = acc[mf][nf][j] + bv;
                if (RELU) vv = fmaxf(vv, 0.0f);
                const long long idx = coff + (long long)(row0 + j) * ldc + col;
                if (RES) vv += res[idx];
                if (OBF16) ((ushort*)Cv)[idx] = f2bf(vv);
                else       ((float*)Cv)[idx]  = vv;
            }
        }
    }
}

// ---------------------------------------------------------------------------
__global__ __launch_bounds__(256) void edge_heads_kernel(
    const float* __restrict__ h, const float* __restrict__ Wfl,
    float* __restrict__ L, float* __restrict__ R)
{
    int row = blockIdx.x * 4 + (threadIdx.x >> 6);
    int lane = threadIdx.x & 63;
    const float* hr = h + (long long)row * DD;
    float accL[NB] = {}, accR[NB] = {};
    #pragma unroll
    for (int tt = 0; tt < 8; ++tt) {
        int e = lane * 8 + tt;
        float hv = hr[e];
        #pragma unroll
        for (int n = 0; n < NB; ++n) {
            accL[n] = fmaf(hv, Wfl[e * NB + n], accL[n]);
            accR[n] = fmaf(hv, Wfl[(DD + e) * NB + n], accR[n]);
        }
    }
    #pragma unroll
    for (int n = 0; n < NB; ++n) {
        #pragma unroll
        for (int off = 1; off < 64; off <<= 1) {
            accL[n] += __shfl_xor(accL[n], off, 64);
            accR[n] += __shfl_xor(accR[n], off, 64);
        }
    }
    if (lane == 0) {
        #pragma unroll
        for (int n = 0; n < NB; ++n) {
            L[row * NB + n] = accL[n];
            R[row * NB + n] = accR[n];
        }
    }
}

__global__ __launch_bounds__(256) void edge_combine_kernel(
    const float* __restrict__ L, const float* __restrict__ R,
    const float* __restrict__ bfl, float* __restrict__ out)
{
    int idx = blockIdx.x * 256 + threadIdx.x;
    int j = idx & 255;
    int bi = idx >> 8;
    int b = bi >> 8;
    float4 l = *(const float4*)&L[bi * NB];
    float4 r = *(const float4*)&R[(b * 256 + j) * NB];
    float4 bf = *(const float4*)bfl;
    float4 o;
    o.x = l.x + r.x + bf.x; o.y = l.y + r.y + bf.y;
    o.z = l.z + r.z + bf.z; o.w = l.w + r.w + bf.w;
    *(float4*)&out[(long long)idx * NB] = o;
}

// ---------------------------------------------------------------------------
extern "C" void kernel_launch(void* const* d_in, const int* in_sizes, int n_in,
                              void* d_out, int out_size, void* d_ws, size_t ws_size,
                              hipStream_t stream)
{
    const int*   src   = (const int*)  d_in[0];
    const float* pe    = (const float*)d_in[3];
    const float* emb   = (const float*)d_in[4];
    const float* Wq    = (const float*)d_in[5];
    const float* Wk    = (const float*)d_in[6];
    const float* Wv    = (const float*)d_in[7];
    const float* Wo    = (const float*)d_in[8];
    const float* W1    = (const float*)d_in[9];
    const float* W2    = (const float*)d_in[10];
    const float* Wfl   = (const float*)d_in[11];
    const float* bq    = (const float*)d_in[12];
    const float* bk    = (const float*)d_in[13];
    const float* bv    = (const float*)d_in[14];
    const float* bo    = (const float*)d_in[15];
    const float* b1    = (const float*)d_in[16];
    const float* b2    = (const float*)d_in[17];
    const float* ln1_b = (const float*)d_in[18];
    const float* ln2_b = (const float*)d_in[19];
    const float* fn_b  = (const float*)d_in[20];
    const float* bfl   = (const float*)d_in[21];
    const float* ln1_a = (const float*)d_in[22];
    const float* ln2_a = (const float*)d_in[23];
    const float* fn_a  = (const float*)d_in[24];
    float* out = (float*)d_out;

    const long long ROWS = (long long)BB * AA;   // 8192
    char* p = (char*)d_ws;
    float*  x    = (float*)p;  p += ROWS * DD * 4;            // 16 MB
    ushort* x2b  = (ushort*)p; p += ROWS * DD * 2;            // 8 MB (LN out / attn out)
    ushort* qkv  = (ushort*)p;                                 // 24 MB
    ushort* h1   = qkv;                                        // h1 aliases qkv+vT (32 MB)
    p += ROWS * 1536 * 2;
    ushort* vT   = (ushort*)p; p += (long long)BB * DD * AA * 2;   // 8 MB
    ushort* Wqkvt= (ushort*)p; p += (long long)NLAYER * 1536 * 512 * 2;
    ushort* Wot  = (ushort*)p; p += (long long)NLAYER * 512 * 512 * 2;
    ushort* W1t  = (ushort*)p; p += (long long)NLAYER * 2048 * 512 * 2;
    ushort* W2t  = (ushort*)p; p += (long long)NLAYER * 512 * 2048 * 2;
    float*  bqkv = (float*)p;  p += (long long)NLAYER * 1536 * 4;
    float*  left = (float*)p;  p += ROWS * NB * 4;
    float*  right= (float*)p;  p += ROWS * NB * 4;

    // ---- weight prep (bf16, K-major) ----
    wtrans_kernel<<<dim3(8, 8, 6),  256, 0, stream>>>(Wq, Wqkvt,          512,  512,  262144LL,  786432LL);
    wtrans_kernel<<<dim3(8, 8, 6),  256, 0, stream>>>(Wk, Wqkvt + 262144, 512,  512,  262144LL,  786432LL);
    wtrans_kernel<<<dim3(8, 8, 6),  256, 0, stream>>>(Wv, Wqkvt + 524288, 512,  512,  262144LL,  786432LL);
    wtrans_kernel<<<dim3(8, 8, 6),  256, 0, stream>>>(Wo, Wot,            512,  512,  262144LL,  262144LL);
    wtrans_kernel<<<dim3(32, 8, 6), 256, 0, stream>>>(W1, W1t,            2048, 512,  1048576LL, 1048576LL);
    wtrans_kernel<<<dim3(8, 32, 6), 256, 0, stream>>>(W2, W2t,            512,  2048, 1048576LL, 1048576LL);
    concat_bias_kernel<<<36, 256, 0, stream>>>(bq, bk, bv, bqkv);

    // ---- embed + PE ----
    embed_pe_kernel<<<4096, 256, 0, stream>>>(src, emb, pe, x);

    for (int i = 0; i < NLAYER; ++i) {
        // LN1 -> bf16
        layernorm512_kernel<true><<<2048, 256, 0, stream>>>(
            x, ln1_a + i * DD, ln1_b + i * DD, x2b);
        // fused QKV projection: [8192x1536], grid 12*32=384
        gemm_wide<16, false><<<384, 512, 0, stream>>>(
            x2b, Wqkvt + (long long)i * 786432, bqkv + i * 1536, qkv,
            512, 512, 1536, 12);
        // V head-transpose
        vtrans_kernel<<<dim3(8, 4, 32), 256, 0, stream>>>(qkv, vT);
        // fused attention (QK^T + softmax + PV) -> x2b
        attn_kernel<<<256, 512, 0, stream>>>(qkv, vT, x2b);
        // x += O@Wo + bo
        gemm_nar<128, 64, 16, false, false, true, true><<<512, 256, 0, stream>>>(
            x2b, Wot + (long long)i * 262144, bo + i * DD, x, x,
            512, 512, 512, 8, 1, 0, 0, 0, 0, 0, 0);
        // LN2 -> bf16
        layernorm512_kernel<true><<<2048, 256, 0, stream>>>(
            x, ln2_a + i * DD, ln2_b + i * DD, x2b);
        // h1 = relu(x2@W1 + b1), grid 16*32=512
        gemm_wide<16, true><<<512, 512, 0, stream>>>(
            x2b, W1t + (long long)i * 1048576, b1 + i * DFF, h1,
            512, 512, 2048, 16);
        // x += h1@W2 + b2
        gemm_nar<128, 64, 64, false, false, true, true><<<512, 256, 0, stream>>>(
            h1, W2t + (long long)i * 1048576, b2 + i * DD, x, x,
            2048, 2048, 512, 8, 1, 0, 0, 0, 0, 0, 0);
    }

    // final norm (fp32, in place), edge heads + combine
    layernorm512_kernel<false><<<2048, 256, 0, stream>>>(x, fn_a, fn_b, x);
    edge_heads_kernel<<<2048, 256, 0, stream>>>(x, Wfl, left, right);
    edge_combine_kernel<<<8192, 256, 0, stream>>>(left, right, bfl, out);
}

// Round 7
// 836.188 us; speedup vs baseline: 1.3796x; 1.0078x over previous
//
#include <hip/hip_runtime.h>
#include <hip/hip_bf16.h>
#include <type_traits>

#define BB 32
#define AA 256
#define DD 512
#define HH 8
#define NLAYER 6
#define DFF 2048
#define NB 4

typedef float  f32x4_t  __attribute__((ext_vector_type(4)));
typedef short  bf16x8_t __attribute__((ext_vector_type(8)));

struct __align__(16) US8 { ushort u[8]; };

__device__ __forceinline__ ushort f2bf(float f) {
    __hip_bfloat16 h = __float2bfloat16(f);
    return *reinterpret_cast<ushort*>(&h);
}
__device__ __forceinline__ float bf2f(ushort u) {
    __hip_bfloat16 h;
    *reinterpret_cast<ushort*>(&h) = u;
    return __bfloat162float(h);
}

// async global->LDS, 16B per lane (dest linear: wave base + lane*16)
__device__ __forceinline__ void gload16(const void* g, void* l) {
    __builtin_amdgcn_global_load_lds(
        (const __attribute__((address_space(1))) void*)g,
        (__attribute__((address_space(3))) void*)l, 16, 0, 0);
}

template<int N> __device__ __forceinline__ void wait_vmcnt() {
    if constexpr      (N == 0)  asm volatile("s_waitcnt vmcnt(0)"  ::: "memory");
    else if constexpr (N == 3)  asm volatile("s_waitcnt vmcnt(3)"  ::: "memory");
    else if constexpr (N == 4)  asm volatile("s_waitcnt vmcnt(4)"  ::: "memory");
    else static_assert(N == 0, "add vmcnt literal");
}
template<int N> using ic = std::integral_constant<int, N>;

// ---------------------------------------------------------------------------
__global__ __launch_bounds__(256) void embed_pe_kernel(
    const int* __restrict__ src, const float* __restrict__ embed,
    const float* __restrict__ pe, float* __restrict__ x)
{
    int t = blockIdx.x * 256 + threadIdx.x;
    int d4 = t & 127;
    int row = t >> 7;
    int a = row & 255;
    int d = d4 * 4;
    int sub = d >> 6;
    int e = d & 63;
    int tok = src[row * 8 + sub];
    float4 em = *(const float4*)&embed[tok * 64 + e];
    float4 p  = *(const float4*)&pe[a * DD + d];
    const float s = 22.627416997969522f;  // sqrt(512)
    float4 r;
    r.x = em.x * s + p.x; r.y = em.y * s + p.y;
    r.z = em.z * s + p.z; r.w = em.w * s + p.w;
    *(float4*)&x[(long long)row * DD + d] = r;
}

// ---------------------------------------------------------------------------
template<bool OB>
__global__ __launch_bounds__(256) void layernorm512_kernel(
    const float* x, const float* __restrict__ alpha,
    const float* __restrict__ beta, void* yv)
{
    const int row = blockIdx.x * 4 + (threadIdx.x >> 6);
    const int lane = threadIdx.x & 63;
    const float* xr = x + (long long)row * DD;
    float4 v0 = *(const float4*)&xr[lane * 8];
    float4 v1 = *(const float4*)&xr[lane * 8 + 4];
    float s  = v0.x + v0.y + v0.z + v0.w + v1.x + v1.y + v1.z + v1.w;
    float ss = v0.x*v0.x + v0.y*v0.y + v0.z*v0.z + v0.w*v0.w
             + v1.x*v1.x + v1.y*v1.y + v1.z*v1.z + v1.w*v1.w;
    #pragma unroll
    for (int off = 1; off < 64; off <<= 1) {
        s  += __shfl_xor(s, off, 64);
        ss += __shfl_xor(ss, off, 64);
    }
    float mu = s * (1.0f / 512.0f);
    float var = fmaxf(ss - 512.0f * mu * mu, 0.0f) * (1.0f / 511.0f);
    float inv = 1.0f / (sqrtf(var) + 1e-6f);
    float4 a0 = *(const float4*)&alpha[lane * 8];
    float4 a1 = *(const float4*)&alpha[lane * 8 + 4];
    float4 b0 = *(const float4*)&beta[lane * 8];
    float4 b1 = *(const float4*)&beta[lane * 8 + 4];
    float o0 = a0.x * (v0.x - mu) * inv + b0.x;
    float o1 = a0.y * (v0.y - mu) * inv + b0.y;
    float o2 = a0.z * (v0.z - mu) * inv + b0.z;
    float o3 = a0.w * (v0.w - mu) * inv + b0.w;
    float o4 = a1.x * (v1.x - mu) * inv + b1.x;
    float o5 = a1.y * (v1.y - mu) * inv + b1.y;
    float o6 = a1.z * (v1.z - mu) * inv + b1.z;
    float o7 = a1.w * (v1.w - mu) * inv + b1.w;
    if (OB) {
        US8 o;
        o.u[0] = f2bf(o0); o.u[1] = f2bf(o1); o.u[2] = f2bf(o2); o.u[3] = f2bf(o3);
        o.u[4] = f2bf(o4); o.u[5] = f2bf(o5); o.u[6] = f2bf(o6); o.u[7] = f2bf(o7);
        *(US8*)((ushort*)yv + (long long)row * DD + lane * 8) = o;
    } else {
        float* yr = (float*)yv + (long long)row * DD + lane * 8;
        float4 w0 = {o0, o1, o2, o3}, w1 = {o4, o5, o6, o7};
        *(float4*)yr = w0;
        *(float4*)(yr + 4) = w1;
    }
}

// ---------------------------------------------------------------------------
__global__ __launch_bounds__(256) void wtrans_kernel(
    const float* __restrict__ src, ushort* __restrict__ dst,
    int Nsz, int Ksz, long long sSrc, long long sDst)
{
    __shared__ float tile[64][65];
    src += blockIdx.z * sSrc;
    dst += blockIdx.z * sDst;
    const int n0 = blockIdx.x * 64, k0 = blockIdx.y * 64;
    const int t = threadIdx.x, col = t & 63, r4 = t >> 6;
    #pragma unroll
    for (int p = 0; p < 16; ++p) {
        int row = p * 4 + r4;
        tile[row][col] = src[(long long)(k0 + row) * Nsz + n0 + col];
    }
    __syncthreads();
    #pragma unroll
    for (int p = 0; p < 16; ++p) {
        int row = p * 4 + r4;
        dst[(long long)(n0 + row) * Ksz + k0 + col] = f2bf(tile[col][row]);
    }
}

__global__ void concat_bias_kernel(const float* __restrict__ bq,
    const float* __restrict__ bk, const float* __restrict__ bv,
    float* __restrict__ o)
{
    int i = blockIdx.x * 256 + threadIdx.x;
    if (i >= NLAYER * 1536) return;
    int l = i / 1536, r = i % 1536;
    float v = r < 512 ? bq[l * 512 + r]
            : (r < 1024 ? bk[l * 512 + r - 512] : bv[l * 512 + r - 1024]);
    o[i] = v;
}

// ---------------------------------------------------------------------------
// Fused attention: one block per (b,h). 8 waves, 2 passes x 16 q-rows/wave.
// qk buffer is [row][1024] (Q|K per row); V comes from vT [b][c][a].
__global__ __launch_bounds__(512, 1) void attn_kernel(
    const ushort* __restrict__ qk, const ushort* __restrict__ vT,
    ushort* __restrict__ Ob)
{
    __shared__ ushort Kl[256 * 64];       // 32 KB  [j][k]
    __shared__ ushort Vl[64 * 256];       // 32 KB  [c][j]
    __shared__ ushort Pl[8 * 16 * 256];   // 64 KB  per-wave [i][j]

    const int t = threadIdx.x;
    const int bh = blockIdx.x;
    const int b = bh >> 3, h = bh & 7;
    const int w = t >> 6, lane = t & 63;
    const int lr = lane & 15, lg = lane >> 4;

    {   // stage K and V^T (pre-swizzled global source, linear LDS dest)
        const int j = t >> 3, slot = t & 7;
        const int chunk = slot ^ (j & 7);
        const ushort* srcK = qk + (long long)(b * 256 + j) * 1024 + 512 + h * 64 + chunk * 8;
        const int c = t >> 5, slv = t & 31;
        const int chv = slv ^ (c & 7);
        const ushort* srcV = vT + (long long)b * 131072 + (long long)(h * 64 + c) * 256 + chv * 8;
        #pragma unroll
        for (int r = 0; r < 4; ++r) {
            gload16(srcK + (long long)r * 64 * 1024, &Kl[(t + r * 512) * 8]);
            gload16(srcV + (long long)r * 16 * 256,  &Vl[(t + r * 512) * 8]);
        }
    }
    asm volatile("s_waitcnt vmcnt(0)" ::: "memory");
    __builtin_amdgcn_sched_barrier(0);
    __builtin_amdgcn_s_barrier();
    __builtin_amdgcn_sched_barrier(0);

    char* Pw = (char*)Pl + w * 8192;
    const char* Kc = (const char*)Kl;
    const char* Vc = (const char*)Vl;

    #pragma unroll 1
    for (int pass = 0; pass < 2; ++pass) {
        const int i0 = pass * 128 + w * 16;
        const ushort* qbase = qk + (long long)(b * 256 + i0 + lr) * 1024 + h * 64 + lg * 8;
        bf16x8_t qf0 = *(const bf16x8_t*)qbase;
        bf16x8_t qf1 = *(const bf16x8_t*)(qbase + 32);

        // S^T = K @ Q^T
        f32x4_t s[16];
        #pragma unroll
        for (int jf = 0; jf < 16; ++jf) s[jf] = (f32x4_t){0.f, 0.f, 0.f, 0.f};
        #pragma unroll
        for (int jf = 0; jf < 16; ++jf) {
            const int row = jf * 16 + lr;
            bf16x8_t k0 = *(const bf16x8_t*)(Kc + row * 128 + ((lg ^ (row & 7)) * 16));
            s[jf] = __builtin_amdgcn_mfma_f32_16x16x32_bf16(k0, qf0, s[jf], 0, 0, 0);
        }
        #pragma unroll
        for (int jf = 0; jf < 16; ++jf) {
            const int row = jf * 16 + lr;
            bf16x8_t k1 = *(const bf16x8_t*)(Kc + row * 128 + (((4 + lg) ^ (row & 7)) * 16));
            s[jf] = __builtin_amdgcn_mfma_f32_16x16x32_bf16(k1, qf1, s[jf], 0, 0, 0);
        }

        // softmax over all 256 j for this lane's i
        float m = -3.0e38f;
        #pragma unroll
        for (int jf = 0; jf < 16; ++jf)
            #pragma unroll
            for (int r = 0; r < 4; ++r) m = fmaxf(m, s[jf][r]);
        m = fmaxf(m, __shfl_xor(m, 16, 64));
        m = fmaxf(m, __shfl_xor(m, 32, 64));
        float l = 0.f;
        #pragma unroll
        for (int jf = 0; jf < 16; ++jf)
            #pragma unroll
            for (int r = 0; r < 4; ++r) {
                float e = __expf((s[jf][r] - m) * 0.125f);
                s[jf][r] = e; l += e;
            }
        l += __shfl_xor(l, 16, 64);
        l += __shfl_xor(l, 32, 64);
        const float inv = 1.0f / l;

        // P -> wave-private LDS, bank-swizzled
        #pragma unroll
        for (int jf = 0; jf < 16; ++jf) {
            ushort4 u;
            u.x = f2bf(s[jf][0] * inv); u.y = f2bf(s[jf][1] * inv);
            u.z = f2bf(s[jf][2] * inv); u.w = f2bf(s[jf][3] * inv);
            const int off = (lr * 512 + jf * 32 + lg * 8) ^ ((lr & 7) << 4);
            *(ushort4*)(Pw + off) = u;
        }
        asm volatile("s_waitcnt lgkmcnt(0)" ::: "memory");
        __builtin_amdgcn_sched_barrier(0);

        // O = P @ V^T
        f32x4_t o[4];
        #pragma unroll
        for (int cf = 0; cf < 4; ++cf) o[cf] = (f32x4_t){0.f, 0.f, 0.f, 0.f};
        #pragma unroll
        for (int ks = 0; ks < 8; ++ks) {
            bf16x8_t pa = *(const bf16x8_t*)(Pw +
                ((lr * 512 + ks * 64 + lg * 16) ^ ((lr & 7) << 4)));
            #pragma unroll
            for (int cf = 0; cf < 4; ++cf) {
                const int crow = cf * 16 + lr;
                bf16x8_t vb = *(const bf16x8_t*)(Vc + crow * 512 +
                    (((ks * 4 + lg) ^ (crow & 7)) * 16));
                o[cf] = __builtin_amdgcn_mfma_f32_16x16x32_bf16(pa, vb, o[cf], 0, 0, 0);
            }
        }
        asm volatile("s_waitcnt lgkmcnt(0)" ::: "memory");
        __builtin_amdgcn_sched_barrier(0);

        #pragma unroll
        for (int cf = 0; cf < 4; ++cf) {
            const int c = cf * 16 + lr;
            #pragma unroll
            for (int r = 0; r < 4; ++r) {
                const int i = i0 + lg * 4 + r;
                Ob[(long long)(b * 256 + i) * 512 + h * 64 + c] = f2bf(o[cf][r]);
            }
        }
    }
}

// ---------------------------------------------------------------------------
// Narrow GEMM: BMt x BNt tile, 256 threads = 4 waves (2x2), wave tile
// (BMt/2)x(BNt/2). 3 LDS buffers, 2 K-tiles in flight, counted vmcnt, ONE
// s_barrier per K-step. Both-side 16B-slot XOR swizzle.
// OUT: 0 = bf16, 1 = fp32 + residual add, 2 = QKV split (cols<1024 -> bf16 C
// at ldc=1024; cols>=1024 -> V head-transposed scatter into C2 [b][c][a]).
template<int BMt, int BNt, int NT, int OUT, bool RELU, bool SWZ>
__global__ __launch_bounds__(256) void gemm_nar(
    const ushort* __restrict__ A, const ushort* __restrict__ B,
    const float* __restrict__ bias, const float* __restrict__ res,
    void* __restrict__ Cv, ushort* __restrict__ C2,
    int lda, int ldb, int ldc, int gx)
{
    constexpr int BK = 32;
    constexpr int AI = (BMt * BK) / 2048;
    constexpr int BI = (BNt * BK) / 2048;
    constexpr int S  = AI + BI;
    constexpr int HM = BMt / 2, HN = BNt / 2;
    constexpr int RM = HM / 16, RN = HN / 16;

    __shared__ ushort As[3][BMt * BK];
    __shared__ ushort Bs[3][BNt * BK];

    const int t = threadIdx.x;
    int nb, mb;
    if (SWZ) {
        const int nwg = gridDim.x, bid = blockIdx.x;
        const int swz = (bid & 7) * (nwg >> 3) + (bid >> 3);
        nb = swz % gx; mb = swz / gx;
    } else {
        nb = blockIdx.x; mb = blockIdx.y;
    }
    const int m0 = mb * BMt, n0 = nb * BNt;

    const int trow  = t >> 2;
    const int tslot = (t & 3) ^ ((t >> 3) & 3);
    const ushort* Ap = A + (long long)(m0 + trow) * lda + tslot * 8;
    const ushort* Bp = B + (long long)(n0 + trow) * ldb + tslot * 8;

    const int w = t >> 6, lane = t & 63;
    const int wr = w >> 1, wc = w & 1;
    const int lr = lane & 15;
    const int slotK = (((lane >> 4) ^ ((lr >> 1) & 3)) * 8);

    f32x4_t acc[RM][RN];
    #pragma unroll
    for (int i = 0; i < RM; ++i)
        #pragma unroll
        for (int j = 0; j < RN; ++j)
            acc[i][j] = (f32x4_t){0.f, 0.f, 0.f, 0.f};

    auto stage = [&](int pf) {
        const int buf = pf % 3;
        const long long ko = (long long)pf * BK;
        #pragma unroll
        for (int i = 0; i < AI; ++i)
            gload16(Ap + ko + (long long)i * 64 * lda, &As[buf][t * 8 + i * 2048]);
        #pragma unroll
        for (int i = 0; i < BI; ++i)
            gload16(Bp + ko + (long long)i * 64 * ldb, &Bs[buf][t * 8 + i * 2048]);
    };

    auto kstep = [&](auto wn, int kt, int pf) {
        wait_vmcnt<decltype(wn)::value>();
        __builtin_amdgcn_sched_barrier(0);
        __builtin_amdgcn_s_barrier();
        __builtin_amdgcn_sched_barrier(0);
        if (pf >= 0) stage(pf);
        __builtin_amdgcn_sched_barrier(0);
        const int cb = kt % 3;
        bf16x8_t af[RM], bfr[RN];
        #pragma unroll
        for (int mf = 0; mf < RM; ++mf)
            af[mf] = *(const bf16x8_t*)&As[cb][(wr * HM + mf * 16 + lr) * BK + slotK];
        #pragma unroll
        for (int nf = 0; nf < RN; ++nf)
            bfr[nf] = *(const bf16x8_t*)&Bs[cb][(wc * HN + nf * 16 + lr) * BK + slotK];
        __builtin_amdgcn_s_setprio(1);
        #pragma unroll
        for (int mf = 0; mf < RM; ++mf)
            #pragma unroll
            for (int nf = 0; nf < RN; ++nf)
                acc[mf][nf] = __builtin_amdgcn_mfma_f32_16x16x32_bf16(
                    af[mf], bfr[nf], acc[mf][nf], 0, 0, 0);
        __builtin_amdgcn_s_setprio(0);
    };

    stage(0);
    stage(1);
    for (int kt = 0; kt < NT - 1; ++kt)
        kstep(ic<S>{}, kt, (kt + 2 < NT) ? (kt + 2) : -1);
    kstep(ic<0>{}, NT - 1, -1);

    #pragma unroll
    for (int nf = 0; nf < RN; ++nf) {
        const int col = n0 + wc * HN + nf * 16 + lr;
        const float bv = bias[col];
        #pragma unroll
        for (int mf = 0; mf < RM; ++mf) {
            const int row0 = m0 + wr * HM + mf * 16 + (lane >> 4) * 4;
            #pragma unroll
            for (int j = 0; j < 4; ++j) {
                float vv = acc[mf][nf][j] + bv;
                if (RELU) vv = fmaxf(vv, 0.0f);
                const int row = row0 + j;
                if (OUT == 0) {
                    ((ushort*)Cv)[(long long)row * ldc + col] = f2bf(vv);
                } else if (OUT == 1) {
                    const long long idx = (long long)row * ldc + col;
                    ((float*)Cv)[idx] = vv + res[idx];
                } else {   // QKV split
                    if (col < 1024) {
                        ((ushort*)Cv)[(long long)row * 1024 + col] = f2bf(vv);
                    } else {
                        const int bq_ = row >> 8, a_ = row & 255;
                        C2[(long long)bq_ * 131072 + (long long)(col - 1024) * 256 + a_] = f2bf(vv);
                    }
                }
            }
        }
    }
}

// ---------------------------------------------------------------------------
__global__ __launch_bounds__(256) void edge_heads_kernel(
    const float* __restrict__ h, const float* __restrict__ Wfl,
    float* __restrict__ L, float* __restrict__ R)
{
    int row = blockIdx.x * 4 + (threadIdx.x >> 6);
    int lane = threadIdx.x & 63;
    const float* hr = h + (long long)row * DD;
    float accL[NB] = {}, accR[NB] = {};
    #pragma unroll
    for (int tt = 0; tt < 8; ++tt) {
        int e = lane * 8 + tt;
        float hv = hr[e];
        #pragma unroll
        for (int n = 0; n < NB; ++n) {
            accL[n] = fmaf(hv, Wfl[e * NB + n], accL[n]);
            accR[n] = fmaf(hv, Wfl[(DD + e) * NB + n], accR[n]);
        }
    }
    #pragma unroll
    for (int n = 0; n < NB; ++n) {
        #pragma unroll
        for (int off = 1; off < 64; off <<= 1) {
            accL[n] += __shfl_xor(accL[n], off, 64);
            accR[n] += __shfl_xor(accR[n], off, 64);
        }
    }
    if (lane == 0) {
        #pragma unroll
        for (int n = 0; n < NB; ++n) {
            L[row * NB + n] = accL[n];
            R[row * NB + n] = accR[n];
        }
    }
}

__global__ __launch_bounds__(256) void edge_combine_kernel(
    const float* __restrict__ L, const float* __restrict__ R,
    const float* __restrict__ bfl, float* __restrict__ out)
{
    int idx = blockIdx.x * 256 + threadIdx.x;
    int j = idx & 255;
    int bi = idx >> 8;
    int b = bi >> 8;
    float4 l = *(const float4*)&L[bi * NB];
    float4 r = *(const float4*)&R[(b * 256 + j) * NB];
    float4 bf = *(const float4*)bfl;
    float4 o;
    o.x = l.x + r.x + bf.x; o.y = l.y + r.y + bf.y;
    o.z = l.z + r.z + bf.z; o.w = l.w + r.w + bf.w;
    *(float4*)&out[(long long)idx * NB] = o;
}

// ---------------------------------------------------------------------------
extern "C" void kernel_launch(void* const* d_in, const int* in_sizes, int n_in,
                              void* d_out, int out_size, void* d_ws, size_t ws_size,
                              hipStream_t stream)
{
    const int*   src   = (const int*)  d_in[0];
    const float* pe    = (const float*)d_in[3];
    const float* emb   = (const float*)d_in[4];
    const float* Wq    = (const float*)d_in[5];
    const float* Wk    = (const float*)d_in[6];
    const float* Wv    = (const float*)d_in[7];
    const float* Wo    = (const float*)d_in[8];
    const float* W1    = (const float*)d_in[9];
    const float* W2    = (const float*)d_in[10];
    const float* Wfl   = (const float*)d_in[11];
    const float* bq    = (const float*)d_in[12];
    const float* bk    = (const float*)d_in[13];
    const float* bv    = (const float*)d_in[14];
    const float* bo    = (const float*)d_in[15];
    const float* b1    = (const float*)d_in[16];
    const float* b2    = (const float*)d_in[17];
    const float* ln1_b = (const float*)d_in[18];
    const float* ln2_b = (const float*)d_in[19];
    const float* fn_b  = (const float*)d_in[20];
    const float* bfl   = (const float*)d_in[21];
    const float* ln1_a = (const float*)d_in[22];
    const float* ln2_a = (const float*)d_in[23];
    const float* fn_a  = (const float*)d_in[24];
    float* out = (float*)d_out;

    const long long ROWS = (long long)BB * AA;   // 8192
    char* p = (char*)d_ws;
    float*  x    = (float*)p;  p += ROWS * DD * 4;                 // 16 MB
    ushort* x2b  = (ushort*)p; p += ROWS * DD * 2;                 // 8 MB (LN out / attn out)
    ushort* qk   = (ushort*)p;                                     // 16 MB [row][1024]
    ushort* h1   = qk;                                             // h1 aliases qk+vT+pad (32 MB)
    p += ROWS * 1024 * 2;
    ushort* vT   = (ushort*)p; p += (long long)BB * DD * AA * 2;   // 8 MB [b][c][a]
    p += 8 * 1024 * 1024;                                          // pad so h1 fits 32 MB
    ushort* Wqkvt= (ushort*)p; p += (long long)NLAYER * 1536 * 512 * 2;
    ushort* Wot  = (ushort*)p; p += (long long)NLAYER * 512 * 512 * 2;
    ushort* W1t  = (ushort*)p; p += (long long)NLAYER * 2048 * 512 * 2;
    ushort* W2t  = (ushort*)p; p += (long long)NLAYER * 512 * 2048 * 2;
    float*  bqkv = (float*)p;  p += (long long)NLAYER * 1536 * 4;
    float*  left = (float*)p;  p += ROWS * NB * 4;
    float*  right= (float*)p;  p += ROWS * NB * 4;

    // ---- weight prep (bf16, K-major) ----
    wtrans_kernel<<<dim3(8, 8, 6),  256, 0, stream>>>(Wq, Wqkvt,          512,  512,  262144LL,  786432LL);
    wtrans_kernel<<<dim3(8, 8, 6),  256, 0, stream>>>(Wk, Wqkvt + 262144, 512,  512,  262144LL,  786432LL);
    wtrans_kernel<<<dim3(8, 8, 6),  256, 0, stream>>>(Wv, Wqkvt + 524288, 512,  512,  262144LL,  786432LL);
    wtrans_kernel<<<dim3(8, 8, 6),  256, 0, stream>>>(Wo, Wot,            512,  512,  262144LL,  262144LL);
    wtrans_kernel<<<dim3(32, 8, 6), 256, 0, stream>>>(W1, W1t,            2048, 512,  1048576LL, 1048576LL);
    wtrans_kernel<<<dim3(8, 32, 6), 256, 0, stream>>>(W2, W2t,            512,  2048, 1048576LL, 1048576LL);
    concat_bias_kernel<<<36, 256, 0, stream>>>(bq, bk, bv, bqkv);

    // ---- embed + PE ----
    embed_pe_kernel<<<4096, 256, 0, stream>>>(src, emb, pe, x);

    for (int i = 0; i < NLAYER; ++i) {
        // LN1 -> bf16
        layernorm512_kernel<true><<<2048, 256, 0, stream>>>(
            x, ln1_a + i * DD, ln1_b + i * DD, x2b);
        // fused QKV projection with V-transpose epilogue: grid 12*64=768
        gemm_nar<128, 128, 16, 2, false, true><<<768, 256, 0, stream>>>(
            x2b, Wqkvt + (long long)i * 786432, bqkv + i * 1536, nullptr,
            qk, vT, 512, 512, 1024, 12);
        // fused attention (QK^T + softmax + PV) -> x2b
        attn_kernel<<<256, 512, 0, stream>>>(qk, vT, x2b);
        // x += O@Wo + bo
        gemm_nar<128, 64, 16, 1, false, true><<<512, 256, 0, stream>>>(
            x2b, Wot + (long long)i * 262144, bo + i * DD, x,
            x, nullptr, 512, 512, 512, 8);
        // LN2 -> bf16
        layernorm512_kernel<true><<<2048, 256, 0, stream>>>(
            x, ln2_a + i * DD, ln2_b + i * DD, x2b);
        // h1 = relu(x2@W1 + b1), grid 16*64=1024
        gemm_nar<128, 128, 16, 0, true, true><<<1024, 256, 0, stream>>>(
            x2b, W1t + (long long)i * 1048576, b1 + i * DFF, nullptr,
            h1, nullptr, 512, 512, 2048, 16);
        // x += h1@W2 + b2
        gemm_nar<128, 64, 64, 1, false, true><<<512, 256, 0, stream>>>(
            h1, W2t + (long long)i * 1048576, b2 + i * DD, x,
            x, nullptr, 2048, 2048, 512, 8);
    }

    // final norm (fp32, in place), edge heads + combine
    layernorm512_kernel<false><<<2048, 256, 0, stream>>>(x, fn_a, fn_b, x);
    edge_heads_kernel<<<2048, 256, 0, stream>>>(x, Wfl, left, right);
    edge_combine_kernel<<<8192, 256, 0, stream>>>(left, right, bfl, out);
}

// Round 8
// 807.088 us; speedup vs baseline: 1.4293x; 1.0361x over previous
//
#include <hip/hip_runtime.h>
#include <hip/hip_bf16.h>

#define BB 32
#define AA 256
#define DD 512
#define HH 8
#define NLAYER 6
#define DFF 2048
#define NB 4

typedef float  f32x4_t  __attribute__((ext_vector_type(4)));
typedef short  bf16x8_t __attribute__((ext_vector_type(8)));

struct __align__(16) US8 { ushort u[8]; };

__device__ __forceinline__ ushort f2bf(float f) {
    __hip_bfloat16 h = __float2bfloat16(f);
    return *reinterpret_cast<ushort*>(&h);
}
__device__ __forceinline__ float bf2f(ushort u) {
    __hip_bfloat16 h;
    *reinterpret_cast<ushort*>(&h) = u;
    return __bfloat162float(h);
}

// async global->LDS, 16B per lane (dest linear: wave base + lane*16)
__device__ __forceinline__ void gload16(const void* g, void* l) {
    __builtin_amdgcn_global_load_lds(
        (const __attribute__((address_space(1))) void*)g,
        (__attribute__((address_space(3))) void*)l, 16, 0, 0);
}

// ---------------------------------------------------------------------------
__global__ __launch_bounds__(256) void embed_pe_kernel(
    const int* __restrict__ src, const float* __restrict__ embed,
    const float* __restrict__ pe, float* __restrict__ x)
{
    int t = blockIdx.x * 256 + threadIdx.x;
    int d4 = t & 127;
    int row = t >> 7;
    int a = row & 255;
    int d = d4 * 4;
    int sub = d >> 6;
    int e = d & 63;
    int tok = src[row * 8 + sub];
    float4 em = *(const float4*)&embed[tok * 64 + e];
    float4 p  = *(const float4*)&pe[a * DD + d];
    const float s = 22.627416997969522f;  // sqrt(512)
    float4 r;
    r.x = em.x * s + p.x; r.y = em.y * s + p.y;
    r.z = em.z * s + p.z; r.w = em.w * s + p.w;
    *(float4*)&x[(long long)row * DD + d] = r;
}

// ---------------------------------------------------------------------------
template<bool OB>
__global__ __launch_bounds__(256) void layernorm512_kernel(
    const float* x, const float* __restrict__ alpha,
    const float* __restrict__ beta, void* yv)
{
    const int row = blockIdx.x * 4 + (threadIdx.x >> 6);
    const int lane = threadIdx.x & 63;
    const float* xr = x + (long long)row * DD;
    float4 v0 = *(const float4*)&xr[lane * 8];
    float4 v1 = *(const float4*)&xr[lane * 8 + 4];
    float s  = v0.x + v0.y + v0.z + v0.w + v1.x + v1.y + v1.z + v1.w;
    float ss = v0.x*v0.x + v0.y*v0.y + v0.z*v0.z + v0.w*v0.w
             + v1.x*v1.x + v1.y*v1.y + v1.z*v1.z + v1.w*v1.w;
    #pragma unroll
    for (int off = 1; off < 64; off <<= 1) {
        s  += __shfl_xor(s, off, 64);
        ss += __shfl_xor(ss, off, 64);
    }
    float mu = s * (1.0f / 512.0f);
    float var = fmaxf(ss - 512.0f * mu * mu, 0.0f) * (1.0f / 511.0f);
    float inv = 1.0f / (sqrtf(var) + 1e-6f);
    float4 a0 = *(const float4*)&alpha[lane * 8];
    float4 a1 = *(const float4*)&alpha[lane * 8 + 4];
    float4 b0 = *(const float4*)&beta[lane * 8];
    float4 b1 = *(const float4*)&beta[lane * 8 + 4];
    float o0 = a0.x * (v0.x - mu) * inv + b0.x;
    float o1 = a0.y * (v0.y - mu) * inv + b0.y;
    float o2 = a0.z * (v0.z - mu) * inv + b0.z;
    float o3 = a0.w * (v0.w - mu) * inv + b0.w;
    float o4 = a1.x * (v1.x - mu) * inv + b1.x;
    float o5 = a1.y * (v1.y - mu) * inv + b1.y;
    float o6 = a1.z * (v1.z - mu) * inv + b1.z;
    float o7 = a1.w * (v1.w - mu) * inv + b1.w;
    if (OB) {
        US8 o;
        o.u[0] = f2bf(o0); o.u[1] = f2bf(o1); o.u[2] = f2bf(o2); o.u[3] = f2bf(o3);
        o.u[4] = f2bf(o4); o.u[5] = f2bf(o5); o.u[6] = f2bf(o6); o.u[7] = f2bf(o7);
        *(US8*)((ushort*)yv + (long long)row * DD + lane * 8) = o;
    } else {
        float* yr = (float*)yv + (long long)row * DD + lane * 8;
        float4 w0 = {o0, o1, o2, o3}, w1 = {o4, o5, o6, o7};
        *(float4*)yr = w0;
        *(float4*)(yr + 4) = w1;
    }
}

// ---------------------------------------------------------------------------
__global__ __launch_bounds__(256) void wtrans_kernel(
    const float* __restrict__ src, ushort* __restrict__ dst,
    int Nsz, int Ksz, long long sSrc, long long sDst)
{
    __shared__ float tile[64][65];
    src += blockIdx.z * sSrc;
    dst += blockIdx.z * sDst;
    const int n0 = blockIdx.x * 64, k0 = blockIdx.y * 64;
    const int t = threadIdx.x, col = t & 63, r4 = t >> 6;
    #pragma unroll
    for (int p = 0; p < 16; ++p) {
        int row = p * 4 + r4;
        tile[row][col] = src[(long long)(k0 + row) * Nsz + n0 + col];
    }
    __syncthreads();
    #pragma unroll
    for (int p = 0; p < 16; ++p) {
        int row = p * 4 + r4;
        dst[(long long)(n0 + row) * Ksz + k0 + col] = f2bf(tile[col][row]);
    }
}

__global__ void concat_bias_kernel(const float* __restrict__ bq,
    const float* __restrict__ bk, const float* __restrict__ bv,
    float* __restrict__ o)
{
    int i = blockIdx.x * 256 + threadIdx.x;
    if (i >= NLAYER * 1536) return;
    int l = i / 1536, r = i % 1536;
    float v = r < 512 ? bq[l * 512 + r]
            : (r < 1024 ? bk[l * 512 + r - 512] : bv[l * 512 + r - 1024]);
    o[i] = v;
}

// ---------------------------------------------------------------------------
// Fused attention: one block per (b,h). 8 waves, 2 passes x 16 q-rows/wave.
// qk buffer is [row][1024] (Q|K per row); V comes from vT [b][c][a].
__global__ __launch_bounds__(512, 1) void attn_kernel(
    const ushort* __restrict__ qk, const ushort* __restrict__ vT,
    ushort* __restrict__ Ob)
{
    __shared__ ushort Kl[256 * 64];       // 32 KB  [j][k]
    __shared__ ushort Vl[64 * 256];       // 32 KB  [c][j]
    __shared__ ushort Pl[8 * 16 * 256];   // 64 KB  per-wave [i][j]

    const int t = threadIdx.x;
    const int bh = blockIdx.x;
    const int b = bh >> 3, h = bh & 7;
    const int w = t >> 6, lane = t & 63;
    const int lr = lane & 15, lg = lane >> 4;

    {   // stage K and V^T (pre-swizzled global source, linear LDS dest)
        const int j = t >> 3, slot = t & 7;
        const int chunk = slot ^ (j & 7);
        const ushort* srcK = qk + (long long)(b * 256 + j) * 1024 + 512 + h * 64 + chunk * 8;
        const int c = t >> 5, slv = t & 31;
        const int chv = slv ^ (c & 7);
        const ushort* srcV = vT + (long long)b * 131072 + (long long)(h * 64 + c) * 256 + chv * 8;
        #pragma unroll
        for (int r = 0; r < 4; ++r) {
            gload16(srcK + (long long)r * 64 * 1024, &Kl[(t + r * 512) * 8]);
            gload16(srcV + (long long)r * 16 * 256,  &Vl[(t + r * 512) * 8]);
        }
    }
    asm volatile("s_waitcnt vmcnt(0)" ::: "memory");
    __builtin_amdgcn_sched_barrier(0);
    __builtin_amdgcn_s_barrier();
    __builtin_amdgcn_sched_barrier(0);

    char* Pw = (char*)Pl + w * 8192;
    const char* Kc = (const char*)Kl;
    const char* Vc = (const char*)Vl;

    #pragma unroll 1
    for (int pass = 0; pass < 2; ++pass) {
        const int i0 = pass * 128 + w * 16;
        const ushort* qbase = qk + (long long)(b * 256 + i0 + lr) * 1024 + h * 64 + lg * 8;
        bf16x8_t qf0 = *(const bf16x8_t*)qbase;
        bf16x8_t qf1 = *(const bf16x8_t*)(qbase + 32);

        // S^T = K @ Q^T
        f32x4_t s[16];
        #pragma unroll
        for (int jf = 0; jf < 16; ++jf) s[jf] = (f32x4_t){0.f, 0.f, 0.f, 0.f};
        #pragma unroll
        for (int jf = 0; jf < 16; ++jf) {
            const int row = jf * 16 + lr;
            bf16x8_t k0 = *(const bf16x8_t*)(Kc + row * 128 + ((lg ^ (row & 7)) * 16));
            s[jf] = __builtin_amdgcn_mfma_f32_16x16x32_bf16(k0, qf0, s[jf], 0, 0, 0);
        }
        #pragma unroll
        for (int jf = 0; jf < 16; ++jf) {
            const int row = jf * 16 + lr;
            bf16x8_t k1 = *(const bf16x8_t*)(Kc + row * 128 + (((4 + lg) ^ (row & 7)) * 16));
            s[jf] = __builtin_amdgcn_mfma_f32_16x16x32_bf16(k1, qf1, s[jf], 0, 0, 0);
        }

        // softmax over all 256 j for this lane's i
        float m = -3.0e38f;
        #pragma unroll
        for (int jf = 0; jf < 16; ++jf)
            #pragma unroll
            for (int r = 0; r < 4; ++r) m = fmaxf(m, s[jf][r]);
        m = fmaxf(m, __shfl_xor(m, 16, 64));
        m = fmaxf(m, __shfl_xor(m, 32, 64));
        float l = 0.f;
        #pragma unroll
        for (int jf = 0; jf < 16; ++jf)
            #pragma unroll
            for (int r = 0; r < 4; ++r) {
                float e = __expf((s[jf][r] - m) * 0.125f);
                s[jf][r] = e; l += e;
            }
        l += __shfl_xor(l, 16, 64);
        l += __shfl_xor(l, 32, 64);
        const float inv = 1.0f / l;

        // P -> wave-private LDS, bank-swizzled
        #pragma unroll
        for (int jf = 0; jf < 16; ++jf) {
            ushort4 u;
            u.x = f2bf(s[jf][0] * inv); u.y = f2bf(s[jf][1] * inv);
            u.z = f2bf(s[jf][2] * inv); u.w = f2bf(s[jf][3] * inv);
            const int off = (lr * 512 + jf * 32 + lg * 8) ^ ((lr & 7) << 4);
            *(ushort4*)(Pw + off) = u;
        }
        asm volatile("s_waitcnt lgkmcnt(0)" ::: "memory");
        __builtin_amdgcn_sched_barrier(0);

        // O = P @ V^T
        f32x4_t o[4];
        #pragma unroll
        for (int cf = 0; cf < 4; ++cf) o[cf] = (f32x4_t){0.f, 0.f, 0.f, 0.f};
        #pragma unroll
        for (int ks = 0; ks < 8; ++ks) {
            bf16x8_t pa = *(const bf16x8_t*)(Pw +
                ((lr * 512 + ks * 64 + lg * 16) ^ ((lr & 7) << 4)));
            #pragma unroll
            for (int cf = 0; cf < 4; ++cf) {
                const int crow = cf * 16 + lr;
                bf16x8_t vb = *(const bf16x8_t*)(Vc + crow * 512 +
                    (((ks * 4 + lg) ^ (crow & 7)) * 16));
                o[cf] = __builtin_amdgcn_mfma_f32_16x16x32_bf16(pa, vb, o[cf], 0, 0, 0);
            }
        }
        asm volatile("s_waitcnt lgkmcnt(0)" ::: "memory");
        __builtin_amdgcn_sched_barrier(0);

        #pragma unroll
        for (int cf = 0; cf < 4; ++cf) {
            const int c = cf * 16 + lr;
            #pragma unroll
            for (int r = 0; r < 4; ++r) {
                const int i = i0 + lg * 4 + r;
                Ob[(long long)(b * 256 + i) * 512 + h * 64 + c] = f2bf(o[cf][r]);
            }
        }
    }
}

// ---------------------------------------------------------------------------
// Narrow GEMM, m97 structure: SINGLE LDS buffer, stage -> __syncthreads
// (drains vmcnt) -> ds_read+MFMA -> __syncthreads. Minimal LDS so 4+ blocks
// co-reside per CU (cross-block wave overlap hides latency, m114/m97).
// Both-side 16B-slot XOR swizzle. 4 waves (2x2), wave tile (BMt/2)x(BNt/2).
// OUT: 0 = bf16, 1 = fp32 + residual add, 2 = QKV split (cols<1024 -> bf16 C
// at ldc=1024; cols>=1024 -> V head-transposed scatter into C2 [b][c][a]).
template<int BMt, int BNt, int NT, int OUT, bool RELU, bool SWZ>
__global__ __launch_bounds__(256, 4) void gemm_nar(
    const ushort* __restrict__ A, const ushort* __restrict__ B,
    const float* __restrict__ bias, const float* __restrict__ res,
    void* __restrict__ Cv, ushort* __restrict__ C2,
    int lda, int ldb, int ldc, int gx)
{
    constexpr int BK = 32;
    constexpr int AI = (BMt * BK) / 2048;
    constexpr int BI = (BNt * BK) / 2048;
    constexpr int HM = BMt / 2, HN = BNt / 2;
    constexpr int RM = HM / 16, RN = HN / 16;

    __shared__ ushort As[BMt * BK];
    __shared__ ushort Bs[BNt * BK];

    const int t = threadIdx.x;
    int nb, mb;
    if (SWZ) {
        const int nwg = gridDim.x, bid = blockIdx.x;
        const int swz = (bid & 7) * (nwg >> 3) + (bid >> 3);
        nb = swz % gx; mb = swz / gx;
    } else {
        nb = blockIdx.x; mb = blockIdx.y;
    }
    const int m0 = mb * BMt, n0 = nb * BNt;

    const int trow  = t >> 2;
    const int tslot = (t & 3) ^ ((t >> 3) & 3);
    const ushort* Ap = A + (long long)(m0 + trow) * lda + tslot * 8;
    const ushort* Bp = B + (long long)(n0 + trow) * ldb + tslot * 8;

    const int w = t >> 6, lane = t & 63;
    const int wr = w >> 1, wc = w & 1;
    const int lr = lane & 15;
    const int slotK = (((lane >> 4) ^ ((lr >> 1) & 3)) * 8);

    f32x4_t acc[RM][RN];
    #pragma unroll
    for (int i = 0; i < RM; ++i)
        #pragma unroll
        for (int j = 0; j < RN; ++j)
            acc[i][j] = (f32x4_t){0.f, 0.f, 0.f, 0.f};

    for (int kt = 0; kt < NT; ++kt) {
        const long long ko = (long long)kt * BK;
        #pragma unroll
        for (int i = 0; i < AI; ++i)
            gload16(Ap + ko + (long long)i * 64 * lda, &As[t * 8 + i * 2048]);
        #pragma unroll
        for (int i = 0; i < BI; ++i)
            gload16(Bp + ko + (long long)i * 64 * ldb, &Bs[t * 8 + i * 2048]);
        __syncthreads();   // drains vmcnt: staged tile visible to all waves

        bf16x8_t af[RM], bfr[RN];
        #pragma unroll
        for (int mf = 0; mf < RM; ++mf)
            af[mf] = *(const bf16x8_t*)&As[(wr * HM + mf * 16 + lr) * BK + slotK];
        #pragma unroll
        for (int nf = 0; nf < RN; ++nf)
            bfr[nf] = *(const bf16x8_t*)&Bs[(wc * HN + nf * 16 + lr) * BK + slotK];
        #pragma unroll
        for (int mf = 0; mf < RM; ++mf)
            #pragma unroll
            for (int nf = 0; nf < RN; ++nf)
                acc[mf][nf] = __builtin_amdgcn_mfma_f32_16x16x32_bf16(
                    af[mf], bfr[nf], acc[mf][nf], 0, 0, 0);
        __syncthreads();   // all waves done reading before next overwrite
    }

    #pragma unroll
    for (int nf = 0; nf < RN; ++nf) {
        const int col = n0 + wc * HN + nf * 16 + lr;
        const float bv = bias[col];
        #pragma unroll
        for (int mf = 0; mf < RM; ++mf) {
            const int row0 = m0 + wr * HM + mf * 16 + (lane >> 4) * 4;
            #pragma unroll
            for (int j = 0; j < 4; ++j) {
                float vv = acc[mf][nf][j] + bv;
                if (RELU) vv = fmaxf(vv, 0.0f);
                const int row = row0 + j;
                if (OUT == 0) {
                    ((ushort*)Cv)[(long long)row * ldc + col] = f2bf(vv);
                } else if (OUT == 1) {
                    const long long idx = (long long)row * ldc + col;
                    ((float*)Cv)[idx] = vv + res[idx];
                } else {   // QKV split
                    if (col < 1024) {
                        ((ushort*)Cv)[(long long)row * 1024 + col] = f2bf(vv);
                    } else {
                        const int bq_ = row >> 8, a_ = row & 255;
                        C2[(long long)bq_ * 131072 + (long long)(col - 1024) * 256 + a_] = f2bf(vv);
                    }
                }
            }
        }
    }
}

// ---------------------------------------------------------------------------
__global__ __launch_bounds__(256) void edge_heads_kernel(
    const float* __restrict__ h, const float* __restrict__ Wfl,
    float* __restrict__ L, float* __restrict__ R)
{
    int row = blockIdx.x * 4 + (threadIdx.x >> 6);
    int lane = threadIdx.x & 63;
    const float* hr = h + (long long)row * DD;
    float accL[NB] = {}, accR[NB] = {};
    #pragma unroll
    for (int tt = 0; tt < 8; ++tt) {
        int e = lane * 8 + tt;
        float hv = hr[e];
        #pragma unroll
        for (int n = 0; n < NB; ++n) {
            accL[n] = fmaf(hv, Wfl[e * NB + n], accL[n]);
            accR[n] = fmaf(hv, Wfl[(DD + e) * NB + n], accR[n]);
        }
    }
    #pragma unroll
    for (int n = 0; n < NB; ++n) {
        #pragma unroll
        for (int off = 1; off < 64; off <<= 1) {
            accL[n] += __shfl_xor(accL[n], off, 64);
            accR[n] += __shfl_xor(accR[n], off, 64);
        }
    }
    if (lane == 0) {
        #pragma unroll
        for (int n = 0; n < NB; ++n) {
            L[row * NB + n] = accL[n];
            R[row * NB + n] = accR[n];
        }
    }
}

__global__ __launch_bounds__(256) void edge_combine_kernel(
    const float* __restrict__ L, const float* __restrict__ R,
    const float* __restrict__ bfl, float* __restrict__ out)
{
    int idx = blockIdx.x * 256 + threadIdx.x;
    int j = idx & 255;
    int bi = idx >> 8;
    int b = bi >> 8;
    float4 l = *(const float4*)&L[bi * NB];
    float4 r = *(const float4*)&R[(b * 256 + j) * NB];
    float4 bf = *(const float4*)bfl;
    float4 o;
    o.x = l.x + r.x + bf.x; o.y = l.y + r.y + bf.y;
    o.z = l.z + r.z + bf.z; o.w = l.w + r.w + bf.w;
    *(float4*)&out[(long long)idx * NB] = o;
}

// ---------------------------------------------------------------------------
extern "C" void kernel_launch(void* const* d_in, const int* in_sizes, int n_in,
                              void* d_out, int out_size, void* d_ws, size_t ws_size,
                              hipStream_t stream)
{
    const int*   src   = (const int*)  d_in[0];
    const float* pe    = (const float*)d_in[3];
    const float* emb   = (const float*)d_in[4];
    const float* Wq    = (const float*)d_in[5];
    const float* Wk    = (const float*)d_in[6];
    const float* Wv    = (const float*)d_in[7];
    const float* Wo    = (const float*)d_in[8];
    const float* W1    = (const float*)d_in[9];
    const float* W2    = (const float*)d_in[10];
    const float* Wfl   = (const float*)d_in[11];
    const float* bq    = (const float*)d_in[12];
    const float* bk    = (const float*)d_in[13];
    const float* bv    = (const float*)d_in[14];
    const float* bo    = (const float*)d_in[15];
    const float* b1    = (const float*)d_in[16];
    const float* b2    = (const float*)d_in[17];
    const float* ln1_b = (const float*)d_in[18];
    const float* ln2_b = (const float*)d_in[19];
    const float* fn_b  = (const float*)d_in[20];
    const float* bfl   = (const float*)d_in[21];
    const float* ln1_a = (const float*)d_in[22];
    const float* ln2_a = (const float*)d_in[23];
    const float* fn_a  = (const float*)d_in[24];
    float* out = (float*)d_out;

    const long long ROWS = (long long)BB * AA;   // 8192
    char* p = (char*)d_ws;
    float*  x    = (float*)p;  p += ROWS * DD * 4;                 // 16 MB
    ushort* x2b  = (ushort*)p; p += ROWS * DD * 2;                 // 8 MB (LN out / attn out)
    ushort* qk   = (ushort*)p;                                     // 16 MB [row][1024]
    ushort* h1   = qk;                                             // h1 aliases qk+vT+pad (32 MB)
    p += ROWS * 1024 * 2;
    ushort* vT   = (ushort*)p; p += (long long)BB * DD * AA * 2;   // 8 MB [b][c][a]
    p += 8 * 1024 * 1024;                                          // pad so h1 fits 32 MB
    ushort* Wqkvt= (ushort*)p; p += (long long)NLAYER * 1536 * 512 * 2;
    ushort* Wot  = (ushort*)p; p += (long long)NLAYER * 512 * 512 * 2;
    ushort* W1t  = (ushort*)p; p += (long long)NLAYER * 2048 * 512 * 2;
    ushort* W2t  = (ushort*)p; p += (long long)NLAYER * 512 * 2048 * 2;
    float*  bqkv = (float*)p;  p += (long long)NLAYER * 1536 * 4;
    float*  left = (float*)p;  p += ROWS * NB * 4;
    float*  right= (float*)p;  p += ROWS * NB * 4;

    // ---- weight prep (bf16, K-major) ----
    wtrans_kernel<<<dim3(8, 8, 6),  256, 0, stream>>>(Wq, Wqkvt,          512,  512,  262144LL,  786432LL);
    wtrans_kernel<<<dim3(8, 8, 6),  256, 0, stream>>>(Wk, Wqkvt + 262144, 512,  512,  262144LL,  786432LL);
    wtrans_kernel<<<dim3(8, 8, 6),  256, 0, stream>>>(Wv, Wqkvt + 524288, 512,  512,  262144LL,  786432LL);
    wtrans_kernel<<<dim3(8, 8, 6),  256, 0, stream>>>(Wo, Wot,            512,  512,  262144LL,  262144LL);
    wtrans_kernel<<<dim3(32, 8, 6), 256, 0, stream>>>(W1, W1t,            2048, 512,  1048576LL, 1048576LL);
    wtrans_kernel<<<dim3(8, 32, 6), 256, 0, stream>>>(W2, W2t,            512,  2048, 1048576LL, 1048576LL);
    concat_bias_kernel<<<36, 256, 0, stream>>>(bq, bk, bv, bqkv);

    // ---- embed + PE ----
    embed_pe_kernel<<<4096, 256, 0, stream>>>(src, emb, pe, x);

    for (int i = 0; i < NLAYER; ++i) {
        // LN1 -> bf16
        layernorm512_kernel<true><<<2048, 256, 0, stream>>>(
            x, ln1_a + i * DD, ln1_b + i * DD, x2b);
        // fused QKV projection with V-transpose epilogue: 128x128, grid 768 (3/CU)
        gemm_nar<128, 128, 16, 2, false, true><<<768, 256, 0, stream>>>(
            x2b, Wqkvt + (long long)i * 786432, bqkv + i * 1536, nullptr,
            qk, vT, 512, 512, 1024, 12);
        // fused attention (QK^T + softmax + PV) -> x2b
        attn_kernel<<<256, 512, 0, stream>>>(qk, vT, x2b);
        // x += O@Wo + bo : 128x64, grid 512
        gemm_nar<128, 64, 16, 1, false, true><<<512, 256, 0, stream>>>(
            x2b, Wot + (long long)i * 262144, bo + i * DD, x,
            x, nullptr, 512, 512, 512, 8);
        // LN2 -> bf16
        layernorm512_kernel<true><<<2048, 256, 0, stream>>>(
            x, ln2_a + i * DD, ln2_b + i * DD, x2b);
        // h1 = relu(x2@W1 + b1): 128x128, grid 1024 (4/CU)
        gemm_nar<128, 128, 16, 0, true, true><<<1024, 256, 0, stream>>>(
            x2b, W1t + (long long)i * 1048576, b1 + i * DFF, nullptr,
            h1, nullptr, 512, 512, 2048, 16);
        // x += h1@W2 + b2 : 64x64 tile, grid 128x8=1024 (4/CU co-residency)
        gemm_nar<64, 64, 64, 1, false, true><<<1024, 256, 0, stream>>>(
            h1, W2t + (long long)i * 1048576, b2 + i * DD, x,
            x, nullptr, 2048, 2048, 512, 8);
    }

    // final norm (fp32, in place), edge heads + combine
    layernorm512_kernel<false><<<2048, 256, 0, stream>>>(x, fn_a, fn_b, x);
    edge_heads_kernel<<<2048, 256, 0, stream>>>(x, Wfl, left, right);
    edge_combine_kernel<<<8192, 256, 0, stream>>>(left, right, bfl, out);
}

// Round 9
// 712.775 us; speedup vs baseline: 1.6185x; 1.1323x over previous
//
#include <hip/hip_runtime.h>
#include <hip/hip_bf16.h>

#define BB 32
#define AA 256
#define DD 512
#define HH 8
#define NLAYER 6
#define DFF 2048
#define NB 4

typedef float  f32x4_t  __attribute__((ext_vector_type(4)));
typedef short  bf16x8_t __attribute__((ext_vector_type(8)));

struct __align__(16) US8 { ushort u[8]; };

__device__ __forceinline__ ushort f2bf(float f) {
    __hip_bfloat16 h = __float2bfloat16(f);
    return *reinterpret_cast<ushort*>(&h);
}
__device__ __forceinline__ float bf2f(ushort u) {
    __hip_bfloat16 h;
    *reinterpret_cast<ushort*>(&h) = u;
    return __bfloat162float(h);
}

// async global->LDS, 16B per lane (dest linear: wave base + lane*16)
__device__ __forceinline__ void gload16(const void* g, void* l) {
    __builtin_amdgcn_global_load_lds(
        (const __attribute__((address_space(1))) void*)g,
        (__attribute__((address_space(3))) void*)l, 16, 0, 0);
}

// ---------------------------------------------------------------------------
__global__ __launch_bounds__(256) void embed_pe_kernel(
    const int* __restrict__ src, const float* __restrict__ embed,
    const float* __restrict__ pe, float* __restrict__ x)
{
    int t = blockIdx.x * 256 + threadIdx.x;
    int d4 = t & 127;
    int row = t >> 7;
    int a = row & 255;
    int d = d4 * 4;
    int sub = d >> 6;
    int e = d & 63;
    int tok = src[row * 8 + sub];
    float4 em = *(const float4*)&embed[tok * 64 + e];
    float4 p  = *(const float4*)&pe[a * DD + d];
    const float s = 22.627416997969522f;  // sqrt(512)
    float4 r;
    r.x = em.x * s + p.x; r.y = em.y * s + p.y;
    r.z = em.z * s + p.z; r.w = em.w * s + p.w;
    *(float4*)&x[(long long)row * DD + d] = r;
}

// ---------------------------------------------------------------------------
template<bool OB>
__global__ __launch_bounds__(256) void layernorm512_kernel(
    const float* x, const float* __restrict__ alpha,
    const float* __restrict__ beta, void* yv)
{
    const int row = blockIdx.x * 4 + (threadIdx.x >> 6);
    const int lane = threadIdx.x & 63;
    const float* xr = x + (long long)row * DD;
    float4 v0 = *(const float4*)&xr[lane * 8];
    float4 v1 = *(const float4*)&xr[lane * 8 + 4];
    float s  = v0.x + v0.y + v0.z + v0.w + v1.x + v1.y + v1.z + v1.w;
    float ss = v0.x*v0.x + v0.y*v0.y + v0.z*v0.z + v0.w*v0.w
             + v1.x*v1.x + v1.y*v1.y + v1.z*v1.z + v1.w*v1.w;
    #pragma unroll
    for (int off = 1; off < 64; off <<= 1) {
        s  += __shfl_xor(s, off, 64);
        ss += __shfl_xor(ss, off, 64);
    }
    float mu = s * (1.0f / 512.0f);
    float var = fmaxf(ss - 512.0f * mu * mu, 0.0f) * (1.0f / 511.0f);
    float inv = 1.0f / (sqrtf(var) + 1e-6f);
    float4 a0 = *(const float4*)&alpha[lane * 8];
    float4 a1 = *(const float4*)&alpha[lane * 8 + 4];
    float4 b0 = *(const float4*)&beta[lane * 8];
    float4 b1 = *(const float4*)&beta[lane * 8 + 4];
    float o0 = a0.x * (v0.x - mu) * inv + b0.x;
    float o1 = a0.y * (v0.y - mu) * inv + b0.y;
    float o2 = a0.z * (v0.z - mu) * inv + b0.z;
    float o3 = a0.w * (v0.w - mu) * inv + b0.w;
    float o4 = a1.x * (v1.x - mu) * inv + b1.x;
    float o5 = a1.y * (v1.y - mu) * inv + b1.y;
    float o6 = a1.z * (v1.z - mu) * inv + b1.z;
    float o7 = a1.w * (v1.w - mu) * inv + b1.w;
    if (OB) {
        US8 o;
        o.u[0] = f2bf(o0); o.u[1] = f2bf(o1); o.u[2] = f2bf(o2); o.u[3] = f2bf(o3);
        o.u[4] = f2bf(o4); o.u[5] = f2bf(o5); o.u[6] = f2bf(o6); o.u[7] = f2bf(o7);
        *(US8*)((ushort*)yv + (long long)row * DD + lane * 8) = o;
    } else {
        float* yr = (float*)yv + (long long)row * DD + lane * 8;
        float4 w0 = {o0, o1, o2, o3}, w1 = {o4, o5, o6, o7};
        *(float4*)yr = w0;
        *(float4*)(yr + 4) = w1;
    }
}

// ---------------------------------------------------------------------------
__global__ __launch_bounds__(256) void wtrans_kernel(
    const float* __restrict__ src, ushort* __restrict__ dst,
    int Nsz, int Ksz, long long sSrc, long long sDst)
{
    __shared__ float tile[64][65];
    src += blockIdx.z * sSrc;
    dst += blockIdx.z * sDst;
    const int n0 = blockIdx.x * 64, k0 = blockIdx.y * 64;
    const int t = threadIdx.x, col = t & 63, r4 = t >> 6;
    #pragma unroll
    for (int p = 0; p < 16; ++p) {
        int row = p * 4 + r4;
        tile[row][col] = src[(long long)(k0 + row) * Nsz + n0 + col];
    }
    __syncthreads();
    #pragma unroll
    for (int p = 0; p < 16; ++p) {
        int row = p * 4 + r4;
        dst[(long long)(n0 + row) * Ksz + k0 + col] = f2bf(tile[col][row]);
    }
}

__global__ void concat_bias_kernel(const float* __restrict__ bq,
    const float* __restrict__ bk, const float* __restrict__ bv,
    float* __restrict__ o)
{
    int i = blockIdx.x * 256 + threadIdx.x;
    if (i >= NLAYER * 1536) return;
    int l = i / 1536, r = i % 1536;
    float v = r < 512 ? bq[l * 512 + r]
            : (r < 1024 ? bk[l * 512 + r - 512] : bv[l * 512 + r - 1024]);
    o[i] = v;
}

// ---------------------------------------------------------------------------
// Fused attention: one block per (b,h). 8 waves, 2 passes x 16 q-rows/wave.
// qk buffer is [row][1024] (Q|K per row); V comes from vT [b][c][a].
__global__ __launch_bounds__(512, 1) void attn_kernel(
    const ushort* __restrict__ qk, const ushort* __restrict__ vT,
    ushort* __restrict__ Ob)
{
    __shared__ ushort Kl[256 * 64];       // 32 KB  [j][k]
    __shared__ ushort Vl[64 * 256];       // 32 KB  [c][j]
    __shared__ ushort Pl[8 * 16 * 256];   // 64 KB  per-wave [i][j]

    const int t = threadIdx.x;
    const int bh = blockIdx.x;
    const int b = bh >> 3, h = bh & 7;
    const int w = t >> 6, lane = t & 63;
    const int lr = lane & 15, lg = lane >> 4;

    {   // stage K and V^T (pre-swizzled global source, linear LDS dest)
        const int j = t >> 3, slot = t & 7;
        const int chunk = slot ^ (j & 7);
        const ushort* srcK = qk + (long long)(b * 256 + j) * 1024 + 512 + h * 64 + chunk * 8;
        const int c = t >> 5, slv = t & 31;
        const int chv = slv ^ (c & 7);
        const ushort* srcV = vT + (long long)b * 131072 + (long long)(h * 64 + c) * 256 + chv * 8;
        #pragma unroll
        for (int r = 0; r < 4; ++r) {
            gload16(srcK + (long long)r * 64 * 1024, &Kl[(t + r * 512) * 8]);
            gload16(srcV + (long long)r * 16 * 256,  &Vl[(t + r * 512) * 8]);
        }
    }
    asm volatile("s_waitcnt vmcnt(0)" ::: "memory");
    __builtin_amdgcn_sched_barrier(0);
    __builtin_amdgcn_s_barrier();
    __builtin_amdgcn_sched_barrier(0);

    char* Pw = (char*)Pl + w * 8192;
    const char* Kc = (const char*)Kl;
    const char* Vc = (const char*)Vl;

    #pragma unroll 1
    for (int pass = 0; pass < 2; ++pass) {
        const int i0 = pass * 128 + w * 16;
        const ushort* qbase = qk + (long long)(b * 256 + i0 + lr) * 1024 + h * 64 + lg * 8;
        bf16x8_t qf0 = *(const bf16x8_t*)qbase;
        bf16x8_t qf1 = *(const bf16x8_t*)(qbase + 32);

        // S^T = K @ Q^T
        f32x4_t s[16];
        #pragma unroll
        for (int jf = 0; jf < 16; ++jf) s[jf] = (f32x4_t){0.f, 0.f, 0.f, 0.f};
        #pragma unroll
        for (int jf = 0; jf < 16; ++jf) {
            const int row = jf * 16 + lr;
            bf16x8_t k0 = *(const bf16x8_t*)(Kc + row * 128 + ((lg ^ (row & 7)) * 16));
            s[jf] = __builtin_amdgcn_mfma_f32_16x16x32_bf16(k0, qf0, s[jf], 0, 0, 0);
        }
        #pragma unroll
        for (int jf = 0; jf < 16; ++jf) {
            const int row = jf * 16 + lr;
            bf16x8_t k1 = *(const bf16x8_t*)(Kc + row * 128 + (((4 + lg) ^ (row & 7)) * 16));
            s[jf] = __builtin_amdgcn_mfma_f32_16x16x32_bf16(k1, qf1, s[jf], 0, 0, 0);
        }

        // softmax over all 256 j for this lane's i
        float m = -3.0e38f;
        #pragma unroll
        for (int jf = 0; jf < 16; ++jf)
            #pragma unroll
            for (int r = 0; r < 4; ++r) m = fmaxf(m, s[jf][r]);
        m = fmaxf(m, __shfl_xor(m, 16, 64));
        m = fmaxf(m, __shfl_xor(m, 32, 64));
        float l = 0.f;
        #pragma unroll
        for (int jf = 0; jf < 16; ++jf)
            #pragma unroll
            for (int r = 0; r < 4; ++r) {
                float e = __expf((s[jf][r] - m) * 0.125f);
                s[jf][r] = e; l += e;
            }
        l += __shfl_xor(l, 16, 64);
        l += __shfl_xor(l, 32, 64);
        const float inv = 1.0f / l;

        // P -> wave-private LDS, bank-swizzled
        #pragma unroll
        for (int jf = 0; jf < 16; ++jf) {
            ushort4 u;
            u.x = f2bf(s[jf][0] * inv); u.y = f2bf(s[jf][1] * inv);
            u.z = f2bf(s[jf][2] * inv); u.w = f2bf(s[jf][3] * inv);
            const int off = (lr * 512 + jf * 32 + lg * 8) ^ ((lr & 7) << 4);
            *(ushort4*)(Pw + off) = u;
        }
        asm volatile("s_waitcnt lgkmcnt(0)" ::: "memory");
        __builtin_amdgcn_sched_barrier(0);

        // O = P @ V^T
        f32x4_t o[4];
        #pragma unroll
        for (int cf = 0; cf < 4; ++cf) o[cf] = (f32x4_t){0.f, 0.f, 0.f, 0.f};
        #pragma unroll
        for (int ks = 0; ks < 8; ++ks) {
            bf16x8_t pa = *(const bf16x8_t*)(Pw +
                ((lr * 512 + ks * 64 + lg * 16) ^ ((lr & 7) << 4)));
            #pragma unroll
            for (int cf = 0; cf < 4; ++cf) {
                const int crow = cf * 16 + lr;
                bf16x8_t vb = *(const bf16x8_t*)(Vc + crow * 512 +
                    (((ks * 4 + lg) ^ (crow & 7)) * 16));
                o[cf] = __builtin_amdgcn_mfma_f32_16x16x32_bf16(pa, vb, o[cf], 0, 0, 0);
            }
        }
        asm volatile("s_waitcnt lgkmcnt(0)" ::: "memory");
        __builtin_amdgcn_sched_barrier(0);

        #pragma unroll
        for (int cf = 0; cf < 4; ++cf) {
            const int c = cf * 16 + lr;
            #pragma unroll
            for (int r = 0; r < 4; ++r) {
                const int i = i0 + lg * 4 + r;
                Ob[(long long)(b * 256 + i) * 512 + h * 64 + c] = f2bf(o[cf][r]);
            }
        }
    }
}

// ---------------------------------------------------------------------------
// Narrow GEMM, m97 single-buffer structure with BK=64 (half the barriers of
// BK=32): stage -> __syncthreads -> 2 k-halves of ds_read+MFMA -> __syncthreads.
// LDS rows are 128 B = 8 x 16B slots; both-side 3-bit XOR swizzle
// (slot ^= row&7): pre-swizzled global source for the linear global_load_lds
// dest + same XOR on fragment reads. 4 waves (2x2), wave tile (BMt/2)x(BNt/2).
// OUT: 0 = bf16, 1 = fp32 + residual add, 2 = QKV split (cols<1024 -> bf16 C
// at ldc=1024; cols>=1024 -> V head-transposed scatter into C2 [b][c][a]).
template<int BMt, int BNt, int NT, int OUT, bool RELU, bool SWZ>
__global__ __launch_bounds__(256, 4) void gemm_nar(
    const ushort* __restrict__ A, const ushort* __restrict__ B,
    const float* __restrict__ bias, const float* __restrict__ res,
    void* __restrict__ Cv, ushort* __restrict__ C2,
    int lda, int ldb, int ldc, int gx)
{
    constexpr int BK = 64;                  // elements; 128-byte LDS rows
    constexpr int AI = BMt / 32;            // 16B issues per thread (A tile)
    constexpr int BI = BNt / 32;
    constexpr int HM = BMt / 2, HN = BNt / 2;
    constexpr int RM = HM / 16, RN = HN / 16;

    __shared__ ushort As[BMt * BK];
    __shared__ ushort Bs[BNt * BK];

    const int t = threadIdx.x;
    int nb, mb;
    if (SWZ) {
        const int nwg = gridDim.x, bid = blockIdx.x;
        const int swz = (bid & 7) * (nwg >> 3) + (bid >> 3);
        nb = swz % gx; mb = swz / gx;
    } else {
        nb = blockIdx.x; mb = blockIdx.y;
    }
    const int m0 = mb * BMt, n0 = nb * BNt;

    // staging: thread t -> row (t>>3) + 32*i, global 16B-chunk (t&7)^(row&7)
    // (32 | i*32 keeps row&7 invariant across issues)
    const int trow  = t >> 3;
    const int tslot = (t & 7) ^ (trow & 7);
    const ushort* Ap = A + (long long)(m0 + trow) * lda + tslot * 8;
    const ushort* Bp = B + (long long)(n0 + trow) * ldb + tslot * 8;

    const int w = t >> 6, lane = t & 63;
    const int wr = w >> 1, wc = w & 1;
    const int lr = lane & 15, lg = lane >> 4;
    const int sx = lr & 7;                  // fragment row & 7 (HM,HN mult. of 8)

    f32x4_t acc[RM][RN];
    #pragma unroll
    for (int i = 0; i < RM; ++i)
        #pragma unroll
        for (int j = 0; j < RN; ++j)
            acc[i][j] = (f32x4_t){0.f, 0.f, 0.f, 0.f};

    for (int kt = 0; kt < NT; ++kt) {
        const long long ko = (long long)kt * BK;
        #pragma unroll
        for (int i = 0; i < AI; ++i)
            gload16(Ap + ko + (long long)i * 32 * lda, &As[t * 8 + i * 2048]);
        #pragma unroll
        for (int i = 0; i < BI; ++i)
            gload16(Bp + ko + (long long)i * 32 * ldb, &Bs[t * 8 + i * 2048]);
        __syncthreads();   // drains vmcnt: staged tile visible to all waves

        #pragma unroll
        for (int kk = 0; kk < 2; ++kk) {
            bf16x8_t af[RM], bfr[RN];
            #pragma unroll
            for (int mf = 0; mf < RM; ++mf)
                af[mf] = *(const bf16x8_t*)
                    &As[(wr * HM + mf * 16 + lr) * BK + (((kk * 4 + lg) ^ sx) * 8)];
            #pragma unroll
            for (int nf = 0; nf < RN; ++nf)
                bfr[nf] = *(const bf16x8_t*)
                    &Bs[(wc * HN + nf * 16 + lr) * BK + (((kk * 4 + lg) ^ sx) * 8)];
            #pragma unroll
            for (int mf = 0; mf < RM; ++mf)
                #pragma unroll
                for (int nf = 0; nf < RN; ++nf)
                    acc[mf][nf] = __builtin_amdgcn_mfma_f32_16x16x32_bf16(
                        af[mf], bfr[nf], acc[mf][nf], 0, 0, 0);
        }
        __syncthreads();   // all waves done reading before next overwrite
    }

    #pragma unroll
    for (int nf = 0; nf < RN; ++nf) {
        const int col = n0 + wc * HN + nf * 16 + lr;
        const float bv = bias[col];
        #pragma unroll
        for (int mf = 0; mf < RM; ++mf) {
            const int row0 = m0 + wr * HM + mf * 16 + lg * 4;
            #pragma unroll
            for (int j = 0; j < 4; ++j) {
                float vv = acc[mf][nf][j] + bv;
                if (RELU) vv = fmaxf(vv, 0.0f);
                const int row = row0 + j;
                if (OUT == 0) {
                    ((ushort*)Cv)[(long long)row * ldc + col] = f2bf(vv);
                } else if (OUT == 1) {
                    const long long idx = (long long)row * ldc + col;
                    ((float*)Cv)[idx] = vv + res[idx];
                } else {   // QKV split
                    if (col < 1024) {
                        ((ushort*)Cv)[(long long)row * 1024 + col] = f2bf(vv);
                    } else {
                        const int bq_ = row >> 8, a_ = row & 255;
                        C2[(long long)bq_ * 131072 + (long long)(col - 1024) * 256 + a_] = f2bf(vv);
                    }
                }
            }
        }
    }
}

// ---------------------------------------------------------------------------
__global__ __launch_bounds__(256) void edge_heads_kernel(
    const float* __restrict__ h, const float* __restrict__ Wfl,
    float* __restrict__ L, float* __restrict__ R)
{
    int row = blockIdx.x * 4 + (threadIdx.x >> 6);
    int lane = threadIdx.x & 63;
    const float* hr = h + (long long)row * DD;
    float accL[NB] = {}, accR[NB] = {};
    #pragma unroll
    for (int tt = 0; tt < 8; ++tt) {
        int e = lane * 8 + tt;
        float hv = hr[e];
        #pragma unroll
        for (int n = 0; n < NB; ++n) {
            accL[n] = fmaf(hv, Wfl[e * NB + n], accL[n]);
            accR[n] = fmaf(hv, Wfl[(DD + e) * NB + n], accR[n]);
        }
    }
    #pragma unroll
    for (int n = 0; n < NB; ++n) {
        #pragma unroll
        for (int off = 1; off < 64; off <<= 1) {
            accL[n] += __shfl_xor(accL[n], off, 64);
            accR[n] += __shfl_xor(accR[n], off, 64);
        }
    }
    if (lane == 0) {
        #pragma unroll
        for (int n = 0; n < NB; ++n) {
            L[row * NB + n] = accL[n];
            R[row * NB + n] = accR[n];
        }
    }
}

__global__ __launch_bounds__(256) void edge_combine_kernel(
    const float* __restrict__ L, const float* __restrict__ R,
    const float* __restrict__ bfl, float* __restrict__ out)
{
    int idx = blockIdx.x * 256 + threadIdx.x;
    int j = idx & 255;
    int bi = idx >> 8;
    int b = bi >> 8;
    float4 l = *(const float4*)&L[bi * NB];
    float4 r = *(const float4*)&R[(b * 256 + j) * NB];
    float4 bf = *(const float4*)bfl;
    float4 o;
    o.x = l.x + r.x + bf.x; o.y = l.y + r.y + bf.y;
    o.z = l.z + r.z + bf.z; o.w = l.w + r.w + bf.w;
    *(float4*)&out[(long long)idx * NB] = o;
}

// ---------------------------------------------------------------------------
extern "C" void kernel_launch(void* const* d_in, const int* in_sizes, int n_in,
                              void* d_out, int out_size, void* d_ws, size_t ws_size,
                              hipStream_t stream)
{
    const int*   src   = (const int*)  d_in[0];
    const float* pe    = (const float*)d_in[3];
    const float* emb   = (const float*)d_in[4];
    const float* Wq    = (const float*)d_in[5];
    const float* Wk    = (const float*)d_in[6];
    const float* Wv    = (const float*)d_in[7];
    const float* Wo    = (const float*)d_in[8];
    const float* W1    = (const float*)d_in[9];
    const float* W2    = (const float*)d_in[10];
    const float* Wfl   = (const float*)d_in[11];
    const float* bq    = (const float*)d_in[12];
    const float* bk    = (const float*)d_in[13];
    const float* bv    = (const float*)d_in[14];
    const float* bo    = (const float*)d_in[15];
    const float* b1    = (const float*)d_in[16];
    const float* b2    = (const float*)d_in[17];
    const float* ln1_b = (const float*)d_in[18];
    const float* ln2_b = (const float*)d_in[19];
    const float* fn_b  = (const float*)d_in[20];
    const float* bfl   = (const float*)d_in[21];
    const float* ln1_a = (const float*)d_in[22];
    const float* ln2_a = (const float*)d_in[23];
    const float* fn_a  = (const float*)d_in[24];
    float* out = (float*)d_out;

    const long long ROWS = (long long)BB * AA;   // 8192
    char* p = (char*)d_ws;
    float*  x    = (float*)p;  p += ROWS * DD * 4;                 // 16 MB
    ushort* x2b  = (ushort*)p; p += ROWS * DD * 2;                 // 8 MB (LN out / attn out)
    ushort* qk   = (ushort*)p;                                     // 16 MB [row][1024]
    ushort* h1   = qk;                                             // h1 aliases qk+vT+pad (32 MB)
    p += ROWS * 1024 * 2;
    ushort* vT   = (ushort*)p; p += (long long)BB * DD * AA * 2;   // 8 MB [b][c][a]
    p += 8 * 1024 * 1024;                                          // pad so h1 fits 32 MB
    ushort* Wqkvt= (ushort*)p; p += (long long)NLAYER * 1536 * 512 * 2;
    ushort* Wot  = (ushort*)p; p += (long long)NLAYER * 512 * 512 * 2;
    ushort* W1t  = (ushort*)p; p += (long long)NLAYER * 2048 * 512 * 2;
    ushort* W2t  = (ushort*)p; p += (long long)NLAYER * 512 * 2048 * 2;
    float*  bqkv = (float*)p;  p += (long long)NLAYER * 1536 * 4;
    float*  left = (float*)p;  p += ROWS * NB * 4;
    float*  right= (float*)p;  p += ROWS * NB * 4;

    // ---- weight prep (bf16, K-major) ----
    wtrans_kernel<<<dim3(8, 8, 6),  256, 0, stream>>>(Wq, Wqkvt,          512,  512,  262144LL,  786432LL);
    wtrans_kernel<<<dim3(8, 8, 6),  256, 0, stream>>>(Wk, Wqkvt + 262144, 512,  512,  262144LL,  786432LL);
    wtrans_kernel<<<dim3(8, 8, 6),  256, 0, stream>>>(Wv, Wqkvt + 524288, 512,  512,  262144LL,  786432LL);
    wtrans_kernel<<<dim3(8, 8, 6),  256, 0, stream>>>(Wo, Wot,            512,  512,  262144LL,  262144LL);
    wtrans_kernel<<<dim3(32, 8, 6), 256, 0, stream>>>(W1, W1t,            2048, 512,  1048576LL, 1048576LL);
    wtrans_kernel<<<dim3(8, 32, 6), 256, 0, stream>>>(W2, W2t,            512,  2048, 1048576LL, 1048576LL);
    concat_bias_kernel<<<36, 256, 0, stream>>>(bq, bk, bv, bqkv);

    // ---- embed + PE ----
    embed_pe_kernel<<<4096, 256, 0, stream>>>(src, emb, pe, x);

    for (int i = 0; i < NLAYER; ++i) {
        // LN1 -> bf16
        layernorm512_kernel<true><<<2048, 256, 0, stream>>>(
            x, ln1_a + i * DD, ln1_b + i * DD, x2b);
        // fused QKV projection with V-transpose epilogue: 128x128, K=512 (NT=8)
        gemm_nar<128, 128, 8, 2, false, true><<<768, 256, 0, stream>>>(
            x2b, Wqkvt + (long long)i * 786432, bqkv + i * 1536, nullptr,
            qk, vT, 512, 512, 1024, 12);
        // fused attention (QK^T + softmax + PV) -> x2b
        attn_kernel<<<256, 512, 0, stream>>>(qk, vT, x2b);
        // x += O@Wo + bo : 128x64, NT=8
        gemm_nar<128, 64, 8, 1, false, true><<<512, 256, 0, stream>>>(
            x2b, Wot + (long long)i * 262144, bo + i * DD, x,
            x, nullptr, 512, 512, 512, 8);
        // LN2 -> bf16
        layernorm512_kernel<true><<<2048, 256, 0, stream>>>(
            x, ln2_a + i * DD, ln2_b + i * DD, x2b);
        // h1 = relu(x2@W1 + b1): 128x128, NT=8, grid 1024 (4/CU)
        gemm_nar<128, 128, 8, 0, true, true><<<1024, 256, 0, stream>>>(
            x2b, W1t + (long long)i * 1048576, b1 + i * DFF, nullptr,
            h1, nullptr, 512, 512, 2048, 16);
        // x += h1@W2 + b2 : 64x64, K=2048 (NT=32), grid 1024 (4/CU)
        gemm_nar<64, 64, 32, 1, false, true><<<1024, 256, 0, stream>>>(
            h1, W2t + (long long)i * 1048576, b2 + i * DD, x,
            x, nullptr, 2048, 2048, 512, 8);
    }

    // final norm (fp32, in place), edge heads + combine
    layernorm512_kernel<false><<<2048, 256, 0, stream>>>(x, fn_a, fn_b, x);
    edge_heads_kernel<<<2048, 256, 0, stream>>>(x, Wfl, left, right);
    edge_combine_kernel<<<8192, 256, 0, stream>>>(left, right, bfl, out);
}

// Round 10
// 706.264 us; speedup vs baseline: 1.6334x; 1.0092x over previous
//
#include <hip/hip_runtime.h>
#include <hip/hip_bf16.h>

#define BB 32
#define AA 256
#define DD 512
#define HH 8
#define NLAYER 6
#define DFF 2048
#define NB 4

typedef float  f32x4_t  __attribute__((ext_vector_type(4)));
typedef short  bf16x8_t __attribute__((ext_vector_type(8)));

struct __align__(16) US8 { ushort u[8]; };

__device__ __forceinline__ ushort f2bf(float f) {
    __hip_bfloat16 h = __float2bfloat16(f);
    return *reinterpret_cast<ushort*>(&h);
}
__device__ __forceinline__ float bf2f(ushort u) {
    __hip_bfloat16 h;
    *reinterpret_cast<ushort*>(&h) = u;
    return __bfloat162float(h);
}

// async global->LDS, 16B per lane (dest linear: wave base + lane*16)
__device__ __forceinline__ void gload16(const void* g, void* l) {
    __builtin_amdgcn_global_load_lds(
        (const __attribute__((address_space(1))) void*)g,
        (__attribute__((address_space(3))) void*)l, 16, 0, 0);
}

// ---------------------------------------------------------------------------
__global__ __launch_bounds__(256) void embed_pe_kernel(
    const int* __restrict__ src, const float* __restrict__ embed,
    const float* __restrict__ pe, float* __restrict__ x)
{
    int t = blockIdx.x * 256 + threadIdx.x;
    int d4 = t & 127;
    int row = t >> 7;
    int a = row & 255;
    int d = d4 * 4;
    int sub = d >> 6;
    int e = d & 63;
    int tok = src[row * 8 + sub];
    float4 em = *(const float4*)&embed[tok * 64 + e];
    float4 p  = *(const float4*)&pe[a * DD + d];
    const float s = 22.627416997969522f;  // sqrt(512)
    float4 r;
    r.x = em.x * s + p.x; r.y = em.y * s + p.y;
    r.z = em.z * s + p.z; r.w = em.w * s + p.w;
    *(float4*)&x[(long long)row * DD + d] = r;
}

// ---------------------------------------------------------------------------
template<bool OB>
__global__ __launch_bounds__(256) void layernorm512_kernel(
    const float* x, const float* __restrict__ alpha,
    const float* __restrict__ beta, void* yv)
{
    const int row = blockIdx.x * 4 + (threadIdx.x >> 6);
    const int lane = threadIdx.x & 63;
    const float* xr = x + (long long)row * DD;
    float4 v0 = *(const float4*)&xr[lane * 8];
    float4 v1 = *(const float4*)&xr[lane * 8 + 4];
    float s  = v0.x + v0.y + v0.z + v0.w + v1.x + v1.y + v1.z + v1.w;
    float ss = v0.x*v0.x + v0.y*v0.y + v0.z*v0.z + v0.w*v0.w
             + v1.x*v1.x + v1.y*v1.y + v1.z*v1.z + v1.w*v1.w;
    #pragma unroll
    for (int off = 1; off < 64; off <<= 1) {
        s  += __shfl_xor(s, off, 64);
        ss += __shfl_xor(ss, off, 64);
    }
    float mu = s * (1.0f / 512.0f);
    float var = fmaxf(ss - 512.0f * mu * mu, 0.0f) * (1.0f / 511.0f);
    float inv = 1.0f / (sqrtf(var) + 1e-6f);
    float4 a0 = *(const float4*)&alpha[lane * 8];
    float4 a1 = *(const float4*)&alpha[lane * 8 + 4];
    float4 b0 = *(const float4*)&beta[lane * 8];
    float4 b1 = *(const float4*)&beta[lane * 8 + 4];
    float o0 = a0.x * (v0.x - mu) * inv + b0.x;
    float o1 = a0.y * (v0.y - mu) * inv + b0.y;
    float o2 = a0.z * (v0.z - mu) * inv + b0.z;
    float o3 = a0.w * (v0.w - mu) * inv + b0.w;
    float o4 = a1.x * (v1.x - mu) * inv + b1.x;
    float o5 = a1.y * (v1.y - mu) * inv + b1.y;
    float o6 = a1.z * (v1.z - mu) * inv + b1.z;
    float o7 = a1.w * (v1.w - mu) * inv + b1.w;
    if (OB) {
        US8 o;
        o.u[0] = f2bf(o0); o.u[1] = f2bf(o1); o.u[2] = f2bf(o2); o.u[3] = f2bf(o3);
        o.u[4] = f2bf(o4); o.u[5] = f2bf(o5); o.u[6] = f2bf(o6); o.u[7] = f2bf(o7);
        *(US8*)((ushort*)yv + (long long)row * DD + lane * 8) = o;
    } else {
        float* yr = (float*)yv + (long long)row * DD + lane * 8;
        float4 w0 = {o0, o1, o2, o3}, w1 = {o4, o5, o6, o7};
        *(float4*)yr = w0;
        *(float4*)(yr + 4) = w1;
    }
}

// ---------------------------------------------------------------------------
__global__ __launch_bounds__(256) void wtrans_kernel(
    const float* __restrict__ src, ushort* __restrict__ dst,
    int Nsz, int Ksz, long long sSrc, long long sDst)
{
    __shared__ float tile[64][65];
    src += blockIdx.z * sSrc;
    dst += blockIdx.z * sDst;
    const int n0 = blockIdx.x * 64, k0 = blockIdx.y * 64;
    const int t = threadIdx.x, col = t & 63, r4 = t >> 6;
    #pragma unroll
    for (int p = 0; p < 16; ++p) {
        int row = p * 4 + r4;
        tile[row][col] = src[(long long)(k0 + row) * Nsz + n0 + col];
    }
    __syncthreads();
    #pragma unroll
    for (int p = 0; p < 16; ++p) {
        int row = p * 4 + r4;
        dst[(long long)(n0 + row) * Ksz + k0 + col] = f2bf(tile[col][row]);
    }
}

__global__ void concat_bias_kernel(const float* __restrict__ bq,
    const float* __restrict__ bk, const float* __restrict__ bv,
    float* __restrict__ o)
{
    int i = blockIdx.x * 256 + threadIdx.x;
    if (i >= NLAYER * 1536) return;
    int l = i / 1536, r = i % 1536;
    float v = r < 512 ? bq[l * 512 + r]
            : (r < 1024 ? bk[l * 512 + r - 512] : bv[l * 512 + r - 1024]);
    o[i] = v;
}

// ---------------------------------------------------------------------------
// Fused attention: one block per (b,h). 8 waves, 2 passes x 16 q-rows/wave.
// qk buffer is [row][1024] (Q|K per row); V comes from vT [b][c][a].
__global__ __launch_bounds__(512, 1) void attn_kernel(
    const ushort* __restrict__ qk, const ushort* __restrict__ vT,
    ushort* __restrict__ Ob)
{
    __shared__ ushort Kl[256 * 64];       // 32 KB  [j][k]
    __shared__ ushort Vl[64 * 256];       // 32 KB  [c][j]
    __shared__ ushort Pl[8 * 16 * 256];   // 64 KB  per-wave [i][j]

    const int t = threadIdx.x;
    const int bh = blockIdx.x;
    const int b = bh >> 3, h = bh & 7;
    const int w = t >> 6, lane = t & 63;
    const int lr = lane & 15, lg = lane >> 4;

    {   // stage K and V^T (pre-swizzled global source, linear LDS dest)
        const int j = t >> 3, slot = t & 7;
        const int chunk = slot ^ (j & 7);
        const ushort* srcK = qk + (long long)(b * 256 + j) * 1024 + 512 + h * 64 + chunk * 8;
        const int c = t >> 5, slv = t & 31;
        const int chv = slv ^ (c & 7);
        const ushort* srcV = vT + (long long)b * 131072 + (long long)(h * 64 + c) * 256 + chv * 8;
        #pragma unroll
        for (int r = 0; r < 4; ++r) {
            gload16(srcK + (long long)r * 64 * 1024, &Kl[(t + r * 512) * 8]);
            gload16(srcV + (long long)r * 16 * 256,  &Vl[(t + r * 512) * 8]);
        }
    }
    asm volatile("s_waitcnt vmcnt(0)" ::: "memory");
    __builtin_amdgcn_sched_barrier(0);
    __builtin_amdgcn_s_barrier();
    __builtin_amdgcn_sched_barrier(0);

    char* Pw = (char*)Pl + w * 8192;
    const char* Kc = (const char*)Kl;
    const char* Vc = (const char*)Vl;

    #pragma unroll 1
    for (int pass = 0; pass < 2; ++pass) {
        const int i0 = pass * 128 + w * 16;
        const ushort* qbase = qk + (long long)(b * 256 + i0 + lr) * 1024 + h * 64 + lg * 8;
        bf16x8_t qf0 = *(const bf16x8_t*)qbase;
        bf16x8_t qf1 = *(const bf16x8_t*)(qbase + 32);

        // S^T = K @ Q^T
        f32x4_t s[16];
        #pragma unroll
        for (int jf = 0; jf < 16; ++jf) s[jf] = (f32x4_t){0.f, 0.f, 0.f, 0.f};
        #pragma unroll
        for (int jf = 0; jf < 16; ++jf) {
            const int row = jf * 16 + lr;
            bf16x8_t k0 = *(const bf16x8_t*)(Kc + row * 128 + ((lg ^ (row & 7)) * 16));
            s[jf] = __builtin_amdgcn_mfma_f32_16x16x32_bf16(k0, qf0, s[jf], 0, 0, 0);
        }
        #pragma unroll
        for (int jf = 0; jf < 16; ++jf) {
            const int row = jf * 16 + lr;
            bf16x8_t k1 = *(const bf16x8_t*)(Kc + row * 128 + (((4 + lg) ^ (row & 7)) * 16));
            s[jf] = __builtin_amdgcn_mfma_f32_16x16x32_bf16(k1, qf1, s[jf], 0, 0, 0);
        }

        // softmax over all 256 j for this lane's i
        float m = -3.0e38f;
        #pragma unroll
        for (int jf = 0; jf < 16; ++jf)
            #pragma unroll
            for (int r = 0; r < 4; ++r) m = fmaxf(m, s[jf][r]);
        m = fmaxf(m, __shfl_xor(m, 16, 64));
        m = fmaxf(m, __shfl_xor(m, 32, 64));
        float l = 0.f;
        #pragma unroll
        for (int jf = 0; jf < 16; ++jf)
            #pragma unroll
            for (int r = 0; r < 4; ++r) {
                float e = __expf((s[jf][r] - m) * 0.125f);
                s[jf][r] = e; l += e;
            }
        l += __shfl_xor(l, 16, 64);
        l += __shfl_xor(l, 32, 64);
        const float inv = 1.0f / l;

        // P -> wave-private LDS, bank-swizzled
        #pragma unroll
        for (int jf = 0; jf < 16; ++jf) {
            ushort4 u;
            u.x = f2bf(s[jf][0] * inv); u.y = f2bf(s[jf][1] * inv);
            u.z = f2bf(s[jf][2] * inv); u.w = f2bf(s[jf][3] * inv);
            const int off = (lr * 512 + jf * 32 + lg * 8) ^ ((lr & 7) << 4);
            *(ushort4*)(Pw + off) = u;
        }
        asm volatile("s_waitcnt lgkmcnt(0)" ::: "memory");
        __builtin_amdgcn_sched_barrier(0);

        // O = P @ V^T
        f32x4_t o[4];
        #pragma unroll
        for (int cf = 0; cf < 4; ++cf) o[cf] = (f32x4_t){0.f, 0.f, 0.f, 0.f};
        #pragma unroll
        for (int ks = 0; ks < 8; ++ks) {
            bf16x8_t pa = *(const bf16x8_t*)(Pw +
                ((lr * 512 + ks * 64 + lg * 16) ^ ((lr & 7) << 4)));
            #pragma unroll
            for (int cf = 0; cf < 4; ++cf) {
                const int crow = cf * 16 + lr;
                bf16x8_t vb = *(const bf16x8_t*)(Vc + crow * 512 +
                    (((ks * 4 + lg) ^ (crow & 7)) * 16));
                o[cf] = __builtin_amdgcn_mfma_f32_16x16x32_bf16(pa, vb, o[cf], 0, 0, 0);
            }
        }
        asm volatile("s_waitcnt lgkmcnt(0)" ::: "memory");
        __builtin_amdgcn_sched_barrier(0);

        #pragma unroll
        for (int cf = 0; cf < 4; ++cf) {
            const int c = cf * 16 + lr;
            #pragma unroll
            for (int r = 0; r < 4; ++r) {
                const int i = i0 + lg * 4 + r;
                Ob[(long long)(b * 256 + i) * 512 + h * 64 + c] = f2bf(o[cf][r]);
            }
        }
    }
}

// ---------------------------------------------------------------------------
// Narrow GEMM, m97 single-buffer structure, template BK (64 or 128 elems):
// stage -> __syncthreads -> BK/32 k-halves of ds_read+MFMA -> __syncthreads.
// LDS rows are BK*2 bytes = SL x 16B slots; both-side 3-bit XOR swizzle
// (slot ^= row&7) keeps staging linear for global_load_lds and fragment
// reads conflict-free (residual 2-way aliasing at SL=16 is free, m136).
// 4 waves (2x2), wave tile (BMt/2)x(BNt/2).
// OUT: 0 = bf16, 1 = fp32 + residual add, 2 = QKV split (cols<1024 -> bf16 C
// at ldc=1024; cols>=1024 -> V head-transposed scatter into C2 [b][c][a]).
template<int BMt, int BNt, int BKt, int NT, int OUT, bool RELU, bool SWZ>
__global__ __launch_bounds__(256, 4) void gemm_nar(
    const ushort* __restrict__ A, const ushort* __restrict__ B,
    const float* __restrict__ bias, const float* __restrict__ res,
    void* __restrict__ Cv, ushort* __restrict__ C2,
    int lda, int ldb, int ldc, int gx)
{
    constexpr int SL  = BKt / 8;            // 16B slots per LDS row
    constexpr int RPI = 2048 / BKt;         // rows staged per issue (256 thr)
    constexpr int AI  = BMt / RPI;
    constexpr int BI  = BNt / RPI;
    constexpr int HM = BMt / 2, HN = BNt / 2;
    constexpr int RM = HM / 16, RN = HN / 16;

    __shared__ ushort As[BMt * BKt];
    __shared__ ushort Bs[BNt * BKt];

    const int t = threadIdx.x;
    int nb, mb;
    if (SWZ) {
        const int nwg = gridDim.x, bid = blockIdx.x;
        const int swz = (bid & 7) * (nwg >> 3) + (bid >> 3);
        nb = swz % gx; mb = swz / gx;
    } else {
        nb = blockIdx.x; mb = blockIdx.y;
    }
    const int m0 = mb * BMt, n0 = nb * BNt;

    // staging: thread t -> row t/SL (+RPI*i), global 16B-chunk (t%SL)^(row&7)
    // (RPI is a multiple of 8, so row&7 is invariant across issues)
    const int trow  = t / SL;
    const int tslot = (t % SL) ^ (trow & 7);
    const ushort* Ap = A + (long long)(m0 + trow) * lda + tslot * 8;
    const ushort* Bp = B + (long long)(n0 + trow) * ldb + tslot * 8;

    const int w = t >> 6, lane = t & 63;
    const int wr = w >> 1, wc = w & 1;
    const int lr = lane & 15, lg = lane >> 4;
    const int sx = lr & 7;                  // fragment row & 7 (HM,HN mult. of 8)

    f32x4_t acc[RM][RN];
    #pragma unroll
    for (int i = 0; i < RM; ++i)
        #pragma unroll
        for (int j = 0; j < RN; ++j)
            acc[i][j] = (f32x4_t){0.f, 0.f, 0.f, 0.f};

    for (int kt = 0; kt < NT; ++kt) {
        const long long ko = (long long)kt * BKt;
        #pragma unroll
        for (int i = 0; i < AI; ++i)
            gload16(Ap + ko + (long long)i * RPI * lda, &As[t * 8 + i * 2048]);
        #pragma unroll
        for (int i = 0; i < BI; ++i)
            gload16(Bp + ko + (long long)i * RPI * ldb, &Bs[t * 8 + i * 2048]);
        __syncthreads();   // drains vmcnt: staged tile visible to all waves

        #pragma unroll
        for (int kk = 0; kk < BKt / 32; ++kk) {
            bf16x8_t af[RM], bfr[RN];
            #pragma unroll
            for (int mf = 0; mf < RM; ++mf)
                af[mf] = *(const bf16x8_t*)
                    &As[(wr * HM + mf * 16 + lr) * BKt + (((kk * 4 + lg) ^ sx) * 8)];
            #pragma unroll
            for (int nf = 0; nf < RN; ++nf)
                bfr[nf] = *(const bf16x8_t*)
                    &Bs[(wc * HN + nf * 16 + lr) * BKt + (((kk * 4 + lg) ^ sx) * 8)];
            #pragma unroll
            for (int mf = 0; mf < RM; ++mf)
                #pragma unroll
                for (int nf = 0; nf < RN; ++nf)
                    acc[mf][nf] = __builtin_amdgcn_mfma_f32_16x16x32_bf16(
                        af[mf], bfr[nf], acc[mf][nf], 0, 0, 0);
        }
        __syncthreads();   // all waves done reading before next overwrite
    }

    #pragma unroll
    for (int nf = 0; nf < RN; ++nf) {
        const int col = n0 + wc * HN + nf * 16 + lr;
        const float bv = bias[col];
        #pragma unroll
        for (int mf = 0; mf < RM; ++mf) {
            const int row0 = m0 + wr * HM + mf * 16 + lg * 4;
            #pragma unroll
            for (int j = 0; j < 4; ++j) {
                float vv = acc[mf][nf][j] + bv;
                if (RELU) vv = fmaxf(vv, 0.0f);
                const int row = row0 + j;
                if (OUT == 0) {
                    ((ushort*)Cv)[(long long)row * ldc + col] = f2bf(vv);
                } else if (OUT == 1) {
                    const long long idx = (long long)row * ldc + col;
                    ((float*)Cv)[idx] = vv + res[idx];
                } else {   // QKV split
                    if (col < 1024) {
                        ((ushort*)Cv)[(long long)row * 1024 + col] = f2bf(vv);
                    } else {
                        const int bq_ = row >> 8, a_ = row & 255;
                        C2[(long long)bq_ * 131072 + (long long)(col - 1024) * 256 + a_] = f2bf(vv);
                    }
                }
            }
        }
    }
}

// ---------------------------------------------------------------------------
// Fused final-norm + edge heads: wave per row; h never hits memory.
__global__ __launch_bounds__(256) void ln_edge_kernel(
    const float* __restrict__ x, const float* __restrict__ alpha,
    const float* __restrict__ beta, const float* __restrict__ Wfl,
    float* __restrict__ L, float* __restrict__ R)
{
    const int row = blockIdx.x * 4 + (threadIdx.x >> 6);
    const int lane = threadIdx.x & 63;
    const float* xr = x + (long long)row * DD;
    float4 v0 = *(const float4*)&xr[lane * 8];
    float4 v1 = *(const float4*)&xr[lane * 8 + 4];
    float s  = v0.x + v0.y + v0.z + v0.w + v1.x + v1.y + v1.z + v1.w;
    float ss = v0.x*v0.x + v0.y*v0.y + v0.z*v0.z + v0.w*v0.w
             + v1.x*v1.x + v1.y*v1.y + v1.z*v1.z + v1.w*v1.w;
    #pragma unroll
    for (int off = 1; off < 64; off <<= 1) {
        s  += __shfl_xor(s, off, 64);
        ss += __shfl_xor(ss, off, 64);
    }
    float mu = s * (1.0f / 512.0f);
    float var = fmaxf(ss - 512.0f * mu * mu, 0.0f) * (1.0f / 511.0f);
    float inv = 1.0f / (sqrtf(var) + 1e-6f);

    float h[8];
    {
        float4 a0 = *(const float4*)&alpha[lane * 8];
        float4 a1 = *(const float4*)&alpha[lane * 8 + 4];
        float4 b0 = *(const float4*)&beta[lane * 8];
        float4 b1 = *(const float4*)&beta[lane * 8 + 4];
        h[0] = a0.x * (v0.x - mu) * inv + b0.x;
        h[1] = a0.y * (v0.y - mu) * inv + b0.y;
        h[2] = a0.z * (v0.z - mu) * inv + b0.z;
        h[3] = a0.w * (v0.w - mu) * inv + b0.w;
        h[4] = a1.x * (v1.x - mu) * inv + b1.x;
        h[5] = a1.y * (v1.y - mu) * inv + b1.y;
        h[6] = a1.z * (v1.z - mu) * inv + b1.z;
        h[7] = a1.w * (v1.w - mu) * inv + b1.w;
    }
    float accL[NB] = {}, accR[NB] = {};
    #pragma unroll
    for (int tt = 0; tt < 8; ++tt) {
        const int e = lane * 8 + tt;
        float4 wl = *(const float4*)&Wfl[e * NB];
        float4 wr = *(const float4*)&Wfl[(DD + e) * NB];
        accL[0] = fmaf(h[tt], wl.x, accL[0]);
        accL[1] = fmaf(h[tt], wl.y, accL[1]);
        accL[2] = fmaf(h[tt], wl.z, accL[2]);
        accL[3] = fmaf(h[tt], wl.w, accL[3]);
        accR[0] = fmaf(h[tt], wr.x, accR[0]);
        accR[1] = fmaf(h[tt], wr.y, accR[1]);
        accR[2] = fmaf(h[tt], wr.z, accR[2]);
        accR[3] = fmaf(h[tt], wr.w, accR[3]);
    }
    #pragma unroll
    for (int n = 0; n < NB; ++n) {
        #pragma unroll
        for (int off = 1; off < 64; off <<= 1) {
            accL[n] += __shfl_xor(accL[n], off, 64);
            accR[n] += __shfl_xor(accR[n], off, 64);
        }
    }
    if (lane == 0) {
        #pragma unroll
        for (int n = 0; n < NB; ++n) {
            L[row * NB + n] = accL[n];
            R[row * NB + n] = accR[n];
        }
    }
}

__global__ __launch_bounds__(256) void edge_combine_kernel(
    const float* __restrict__ L, const float* __restrict__ R,
    const float* __restrict__ bfl, float* __restrict__ out)
{
    int idx = blockIdx.x * 256 + threadIdx.x;
    int j = idx & 255;
    int bi = idx >> 8;
    int b = bi >> 8;
    float4 l = *(const float4*)&L[bi * NB];
    float4 r = *(const float4*)&R[(b * 256 + j) * NB];
    float4 bf = *(const float4*)bfl;
    float4 o;
    o.x = l.x + r.x + bf.x; o.y = l.y + r.y + bf.y;
    o.z = l.z + r.z + bf.z; o.w = l.w + r.w + bf.w;
    *(float4*)&out[(long long)idx * NB] = o;
}

// ---------------------------------------------------------------------------
extern "C" void kernel_launch(void* const* d_in, const int* in_sizes, int n_in,
                              void* d_out, int out_size, void* d_ws, size_t ws_size,
                              hipStream_t stream)
{
    const int*   src   = (const int*)  d_in[0];
    const float* pe    = (const float*)d_in[3];
    const float* emb   = (const float*)d_in[4];
    const float* Wq    = (const float*)d_in[5];
    const float* Wk    = (const float*)d_in[6];
    const float* Wv    = (const float*)d_in[7];
    const float* Wo    = (const float*)d_in[8];
    const float* W1    = (const float*)d_in[9];
    const float* W2    = (const float*)d_in[10];
    const float* Wfl   = (const float*)d_in[11];
    const float* bq    = (const float*)d_in[12];
    const float* bk    = (const float*)d_in[13];
    const float* bv    = (const float*)d_in[14];
    const float* bo    = (const float*)d_in[15];
    const float* b1    = (const float*)d_in[16];
    const float* b2    = (const float*)d_in[17];
    const float* ln1_b = (const float*)d_in[18];
    const float* ln2_b = (const float*)d_in[19];
    const float* fn_b  = (const float*)d_in[20];
    const float* bfl   = (const float*)d_in[21];
    const float* ln1_a = (const float*)d_in[22];
    const float* ln2_a = (const float*)d_in[23];
    const float* fn_a  = (const float*)d_in[24];
    float* out = (float*)d_out;

    const long long ROWS = (long long)BB * AA;   // 8192
    char* p = (char*)d_ws;
    float*  x    = (float*)p;  p += ROWS * DD * 4;                 // 16 MB
    ushort* x2b  = (ushort*)p; p += ROWS * DD * 2;                 // 8 MB (LN out / attn out)
    ushort* qk   = (ushort*)p;                                     // 16 MB [row][1024]
    ushort* h1   = qk;                                             // h1 aliases qk+vT+pad (32 MB)
    p += ROWS * 1024 * 2;
    ushort* vT   = (ushort*)p; p += (long long)BB * DD * AA * 2;   // 8 MB [b][c][a]
    p += 8 * 1024 * 1024;                                          // pad so h1 fits 32 MB
    ushort* Wqkvt= (ushort*)p; p += (long long)NLAYER * 1536 * 512 * 2;
    ushort* Wot  = (ushort*)p; p += (long long)NLAYER * 512 * 512 * 2;
    ushort* W1t  = (ushort*)p; p += (long long)NLAYER * 2048 * 512 * 2;
    ushort* W2t  = (ushort*)p; p += (long long)NLAYER * 512 * 2048 * 2;
    float*  bqkv = (float*)p;  p += (long long)NLAYER * 1536 * 4;
    float*  left = (float*)p;  p += ROWS * NB * 4;
    float*  right= (float*)p;  p += ROWS * NB * 4;

    // ---- weight prep (bf16, K-major) ----
    wtrans_kernel<<<dim3(8, 8, 6),  256, 0, stream>>>(Wq, Wqkvt,          512,  512,  262144LL,  786432LL);
    wtrans_kernel<<<dim3(8, 8, 6),  256, 0, stream>>>(Wk, Wqkvt + 262144, 512,  512,  262144LL,  786432LL);
    wtrans_kernel<<<dim3(8, 8, 6),  256, 0, stream>>>(Wv, Wqkvt + 524288, 512,  512,  262144LL,  786432LL);
    wtrans_kernel<<<dim3(8, 8, 6),  256, 0, stream>>>(Wo, Wot,            512,  512,  262144LL,  262144LL);
    wtrans_kernel<<<dim3(32, 8, 6), 256, 0, stream>>>(W1, W1t,            2048, 512,  1048576LL, 1048576LL);
    wtrans_kernel<<<dim3(8, 32, 6), 256, 0, stream>>>(W2, W2t,            512,  2048, 1048576LL, 1048576LL);
    concat_bias_kernel<<<36, 256, 0, stream>>>(bq, bk, bv, bqkv);

    // ---- embed + PE ----
    embed_pe_kernel<<<4096, 256, 0, stream>>>(src, emb, pe, x);

    for (int i = 0; i < NLAYER; ++i) {
        // LN1 -> bf16
        layernorm512_kernel<true><<<2048, 256, 0, stream>>>(
            x, ln1_a + i * DD, ln1_b + i * DD, x2b);
        // fused QKV projection with V-transpose epilogue: 128x128, BK=64 (NT=8)
        gemm_nar<128, 128, 64, 8, 2, false, true><<<768, 256, 0, stream>>>(
            x2b, Wqkvt + (long long)i * 786432, bqkv + i * 1536, nullptr,
            qk, vT, 512, 512, 1024, 12);
        // fused attention (QK^T + softmax + PV) -> x2b
        attn_kernel<<<256, 512, 0, stream>>>(qk, vT, x2b);
        // x += O@Wo + bo : 128x64, BK=64 (NT=8)
        gemm_nar<128, 64, 64, 8, 1, false, true><<<512, 256, 0, stream>>>(
            x2b, Wot + (long long)i * 262144, bo + i * DD, x,
            x, nullptr, 512, 512, 512, 8);
        // LN2 -> bf16
        layernorm512_kernel<true><<<2048, 256, 0, stream>>>(
            x, ln2_a + i * DD, ln2_b + i * DD, x2b);
        // h1 = relu(x2@W1 + b1): 128x128, BK=64 (NT=8), grid 1024 (4/CU)
        gemm_nar<128, 128, 64, 8, 0, true, true><<<1024, 256, 0, stream>>>(
            x2b, W1t + (long long)i * 1048576, b1 + i * DFF, nullptr,
            h1, nullptr, 512, 512, 2048, 16);
        // x += h1@W2 + b2 : 64x64, BK=128 (NT=16), grid 1024 (4/CU)
        gemm_nar<64, 64, 128, 16, 1, false, true><<<1024, 256, 0, stream>>>(
            h1, W2t + (long long)i * 1048576, b2 + i * DD, x,
            x, nullptr, 2048, 2048, 512, 8);
    }

    // fused final norm + edge heads, then combine
    ln_edge_kernel<<<2048, 256, 0, stream>>>(x, fn_a, fn_b, Wfl, left, right);
    edge_combine_kernel<<<8192, 256, 0, stream>>>(left, right, bfl, out);
}

// Round 11
// 697.778 us; speedup vs baseline: 1.6532x; 1.0122x over previous
//
#include <hip/hip_runtime.h>
#include <hip/hip_bf16.h>

#define BB 32
#define AA 256
#define DD 512
#define HH 8
#define NLAYER 6
#define DFF 2048
#define NB 4

typedef float  f32x4_t  __attribute__((ext_vector_type(4)));
typedef short  bf16x8_t __attribute__((ext_vector_type(8)));

struct __align__(16) US8 { ushort u[8]; };

__device__ __forceinline__ ushort f2bf(float f) {
    __hip_bfloat16 h = __float2bfloat16(f);
    return *reinterpret_cast<ushort*>(&h);
}
__device__ __forceinline__ float bf2f(ushort u) {
    __hip_bfloat16 h;
    *reinterpret_cast<ushort*>(&h) = u;
    return __bfloat162float(h);
}

// async global->LDS, 16B per lane (dest linear: wave base + lane*16)
__device__ __forceinline__ void gload16(const void* g, void* l) {
    __builtin_amdgcn_global_load_lds(
        (const __attribute__((address_space(1))) void*)g,
        (__attribute__((address_space(3))) void*)l, 16, 0, 0);
}

// ---------------------------------------------------------------------------
__global__ __launch_bounds__(256) void embed_pe_kernel(
    const int* __restrict__ src, const float* __restrict__ embed,
    const float* __restrict__ pe, float* __restrict__ x)
{
    int t = blockIdx.x * 256 + threadIdx.x;
    int d4 = t & 127;
    int row = t >> 7;
    int a = row & 255;
    int d = d4 * 4;
    int sub = d >> 6;
    int e = d & 63;
    int tok = src[row * 8 + sub];
    float4 em = *(const float4*)&embed[tok * 64 + e];
    float4 p  = *(const float4*)&pe[a * DD + d];
    const float s = 22.627416997969522f;  // sqrt(512)
    float4 r;
    r.x = em.x * s + p.x; r.y = em.y * s + p.y;
    r.z = em.z * s + p.z; r.w = em.w * s + p.w;
    *(float4*)&x[(long long)row * DD + d] = r;
}

// ---------------------------------------------------------------------------
template<bool OB>
__global__ __launch_bounds__(256) void layernorm512_kernel(
    const float* x, const float* __restrict__ alpha,
    const float* __restrict__ beta, void* yv)
{
    const int row = blockIdx.x * 4 + (threadIdx.x >> 6);
    const int lane = threadIdx.x & 63;
    const float* xr = x + (long long)row * DD;
    float4 v0 = *(const float4*)&xr[lane * 8];
    float4 v1 = *(const float4*)&xr[lane * 8 + 4];
    float s  = v0.x + v0.y + v0.z + v0.w + v1.x + v1.y + v1.z + v1.w;
    float ss = v0.x*v0.x + v0.y*v0.y + v0.z*v0.z + v0.w*v0.w
             + v1.x*v1.x + v1.y*v1.y + v1.z*v1.z + v1.w*v1.w;
    #pragma unroll
    for (int off = 1; off < 64; off <<= 1) {
        s  += __shfl_xor(s, off, 64);
        ss += __shfl_xor(ss, off, 64);
    }
    float mu = s * (1.0f / 512.0f);
    float var = fmaxf(ss - 512.0f * mu * mu, 0.0f) * (1.0f / 511.0f);
    float inv = 1.0f / (sqrtf(var) + 1e-6f);
    float4 a0 = *(const float4*)&alpha[lane * 8];
    float4 a1 = *(const float4*)&alpha[lane * 8 + 4];
    float4 b0 = *(const float4*)&beta[lane * 8];
    float4 b1 = *(const float4*)&beta[lane * 8 + 4];
    float o0 = a0.x * (v0.x - mu) * inv + b0.x;
    float o1 = a0.y * (v0.y - mu) * inv + b0.y;
    float o2 = a0.z * (v0.z - mu) * inv + b0.z;
    float o3 = a0.w * (v0.w - mu) * inv + b0.w;
    float o4 = a1.x * (v1.x - mu) * inv + b1.x;
    float o5 = a1.y * (v1.y - mu) * inv + b1.y;
    float o6 = a1.z * (v1.z - mu) * inv + b1.z;
    float o7 = a1.w * (v1.w - mu) * inv + b1.w;
    if (OB) {
        US8 o;
        o.u[0] = f2bf(o0); o.u[1] = f2bf(o1); o.u[2] = f2bf(o2); o.u[3] = f2bf(o3);
        o.u[4] = f2bf(o4); o.u[5] = f2bf(o5); o.u[6] = f2bf(o6); o.u[7] = f2bf(o7);
        *(US8*)((ushort*)yv + (long long)row * DD + lane * 8) = o;
    } else {
        float* yr = (float*)yv + (long long)row * DD + lane * 8;
        float4 w0 = {o0, o1, o2, o3}, w1 = {o4, o5, o6, o7};
        *(float4*)yr = w0;
        *(float4*)(yr + 4) = w1;
    }
}

// ---------------------------------------------------------------------------
// Generic weight transpose fp32[K][N] -> bf16[N][K] (for W1, W2)
__global__ __launch_bounds__(256) void wtrans_kernel(
    const float* __restrict__ src, ushort* __restrict__ dst,
    int Nsz, int Ksz, long long sSrc, long long sDst)
{
    __shared__ float tile[64][65];
    src += blockIdx.z * sSrc;
    dst += blockIdx.z * sDst;
    const int n0 = blockIdx.x * 64, k0 = blockIdx.y * 64;
    const int t = threadIdx.x, col = t & 63, r4 = t >> 6;
    #pragma unroll
    for (int p = 0; p < 16; ++p) {
        int row = p * 4 + r4;
        tile[row][col] = src[(long long)(k0 + row) * Nsz + n0 + col];
    }
    __syncthreads();
    #pragma unroll
    for (int p = 0; p < 16; ++p) {
        int row = p * 4 + r4;
        dst[(long long)(n0 + row) * Ksz + k0 + col] = f2bf(tile[col][row]);
    }
}

// Merged transpose for the four 512x512 weights: z = layer*4 + {Wq,Wk,Wv,Wo}
__global__ __launch_bounds__(256) void wtrans4_kernel(
    const float* __restrict__ Wq, const float* __restrict__ Wk,
    const float* __restrict__ Wv, const float* __restrict__ Wo,
    ushort* __restrict__ Wqkvt, ushort* __restrict__ Wot)
{
    __shared__ float tile[64][65];
    const int z = blockIdx.z, layer = z >> 2, mat = z & 3;
    const float* src = (mat == 0 ? Wq : mat == 1 ? Wk : mat == 2 ? Wv : Wo)
                     + (long long)layer * 262144;
    ushort* dst = (mat < 3)
        ? Wqkvt + (long long)layer * 786432 + (long long)mat * 262144
        : Wot + (long long)layer * 262144;
    const int n0 = blockIdx.x * 64, k0 = blockIdx.y * 64;
    const int t = threadIdx.x, col = t & 63, r4 = t >> 6;
    #pragma unroll
    for (int p = 0; p < 16; ++p) {
        int row = p * 4 + r4;
        tile[row][col] = src[(long long)(k0 + row) * 512 + n0 + col];
    }
    __syncthreads();
    #pragma unroll
    for (int p = 0; p < 16; ++p) {
        int row = p * 4 + r4;
        dst[(long long)(n0 + row) * 512 + k0 + col] = f2bf(tile[col][row]);
    }
}

__global__ void concat_bias_kernel(const float* __restrict__ bq,
    const float* __restrict__ bk, const float* __restrict__ bv,
    float* __restrict__ o)
{
    int i = blockIdx.x * 256 + threadIdx.x;
    if (i >= NLAYER * 1536) return;
    int l = i / 1536, r = i % 1536;
    float v = r < 512 ? bq[l * 512 + r]
            : (r < 1024 ? bk[l * 512 + r - 512] : bv[l * 512 + r - 1024]);
    o[i] = v;
}

// ---------------------------------------------------------------------------
// Fused attention: one block per (b,h). 8 waves, 2 passes x 16 q-rows/wave.
// LDS = K(32K) + V(32K) + P-chunks(16K) = 80 KB -> 2 blocks/CU co-residency.
// P is processed in 4 j-quarter chunks of 2 KB/wave (write chunk -> lgkm ->
// 2 PV k-steps), same XOR involution on 128-B rows.
__global__ __launch_bounds__(512, 4) void attn_kernel(
    const ushort* __restrict__ qk, const ushort* __restrict__ vT,
    ushort* __restrict__ Ob)
{
    __shared__ ushort Kl[256 * 64];       // 32 KB  [j][k]
    __shared__ ushort Vl[64 * 256];       // 32 KB  [c][j]
    __shared__ ushort Pl[8 * 16 * 64];    // 16 KB  per-wave [i][j-quarter]

    const int t = threadIdx.x;
    const int bh = blockIdx.x;
    const int b = bh >> 3, h = bh & 7;
    const int w = t >> 6, lane = t & 63;
    const int lr = lane & 15, lg = lane >> 4;

    {   // stage K and V^T (pre-swizzled global source, linear LDS dest)
        const int j = t >> 3, slot = t & 7;
        const int chunk = slot ^ (j & 7);
        const ushort* srcK = qk + (long long)(b * 256 + j) * 1024 + 512 + h * 64 + chunk * 8;
        const int c = t >> 5, slv = t & 31;
        const int chv = slv ^ (c & 7);
        const ushort* srcV = vT + (long long)b * 131072 + (long long)(h * 64 + c) * 256 + chv * 8;
        #pragma unroll
        for (int r = 0; r < 4; ++r) {
            gload16(srcK + (long long)r * 64 * 1024, &Kl[(t + r * 512) * 8]);
            gload16(srcV + (long long)r * 16 * 256,  &Vl[(t + r * 512) * 8]);
        }
    }
    asm volatile("s_waitcnt vmcnt(0)" ::: "memory");
    __builtin_amdgcn_sched_barrier(0);
    __builtin_amdgcn_s_barrier();
    __builtin_amdgcn_sched_barrier(0);

    char* Pw = (char*)Pl + w * 2048;
    const char* Kc = (const char*)Kl;
    const char* Vc = (const char*)Vl;

    #pragma unroll 1
    for (int pass = 0; pass < 2; ++pass) {
        const int i0 = pass * 128 + w * 16;
        const ushort* qbase = qk + (long long)(b * 256 + i0 + lr) * 1024 + h * 64 + lg * 8;
        bf16x8_t qf0 = *(const bf16x8_t*)qbase;
        bf16x8_t qf1 = *(const bf16x8_t*)(qbase + 32);

        // S^T = K @ Q^T  (lane (lg,lr): i = i0+lr, j = jf*16 + lg*4 + r)
        f32x4_t s[16];
        #pragma unroll
        for (int jf = 0; jf < 16; ++jf) s[jf] = (f32x4_t){0.f, 0.f, 0.f, 0.f};
        #pragma unroll
        for (int jf = 0; jf < 16; ++jf) {
            const int row = jf * 16 + lr;
            bf16x8_t k0 = *(const bf16x8_t*)(Kc + row * 128 + ((lg ^ (row & 7)) * 16));
            s[jf] = __builtin_amdgcn_mfma_f32_16x16x32_bf16(k0, qf0, s[jf], 0, 0, 0);
        }
        #pragma unroll
        for (int jf = 0; jf < 16; ++jf) {
            const int row = jf * 16 + lr;
            bf16x8_t k1 = *(const bf16x8_t*)(Kc + row * 128 + (((4 + lg) ^ (row & 7)) * 16));
            s[jf] = __builtin_amdgcn_mfma_f32_16x16x32_bf16(k1, qf1, s[jf], 0, 0, 0);
        }

        // softmax over all 256 j for this lane's i
        float m = -3.0e38f;
        #pragma unroll
        for (int jf = 0; jf < 16; ++jf)
            #pragma unroll
            for (int r = 0; r < 4; ++r) m = fmaxf(m, s[jf][r]);
        m = fmaxf(m, __shfl_xor(m, 16, 64));
        m = fmaxf(m, __shfl_xor(m, 32, 64));
        float l = 0.f;
        #pragma unroll
        for (int jf = 0; jf < 16; ++jf)
            #pragma unroll
            for (int r = 0; r < 4; ++r) {
                float e = __expf((s[jf][r] - m) * 0.125f);
                s[jf][r] = e; l += e;
            }
        l += __shfl_xor(l, 16, 64);
        l += __shfl_xor(l, 32, 64);
        const float inv = 1.0f / l;

        // O = P @ V^T, j processed in 4 quarter-chunks of 64
        f32x4_t o[4];
        #pragma unroll
        for (int cf = 0; cf < 4; ++cf) o[cf] = (f32x4_t){0.f, 0.f, 0.f, 0.f};
        #pragma unroll
        for (int jq = 0; jq < 4; ++jq) {
            // prior chunk's reads complete before overwrite (wave-private)
            asm volatile("s_waitcnt lgkmcnt(0)" ::: "memory");
            __builtin_amdgcn_sched_barrier(0);
            #pragma unroll
            for (int jf4 = 0; jf4 < 4; ++jf4) {
                const int jf = jq * 4 + jf4;
                ushort4 u;
                u.x = f2bf(s[jf][0] * inv); u.y = f2bf(s[jf][1] * inv);
                u.z = f2bf(s[jf][2] * inv); u.w = f2bf(s[jf][3] * inv);
                const int off = (lr * 128 + jf4 * 32 + lg * 8) ^ ((lr & 7) << 4);
                *(ushort4*)(Pw + off) = u;
            }
            asm volatile("s_waitcnt lgkmcnt(0)" ::: "memory");   // writes committed
            __builtin_amdgcn_sched_barrier(0);
            #pragma unroll
            for (int ks2 = 0; ks2 < 2; ++ks2) {
                const int ks = jq * 2 + ks2;
                bf16x8_t pa = *(const bf16x8_t*)(Pw +
                    ((lr * 128 + ks2 * 64 + lg * 16) ^ ((lr & 7) << 4)));
                #pragma unroll
                for (int cf = 0; cf < 4; ++cf) {
                    const int crow = cf * 16 + lr;
                    bf16x8_t vb = *(const bf16x8_t*)(Vc + crow * 512 +
                        (((ks * 4 + lg) ^ (crow & 7)) * 16));
                    o[cf] = __builtin_amdgcn_mfma_f32_16x16x32_bf16(pa, vb, o[cf], 0, 0, 0);
                }
            }
        }
        asm volatile("s_waitcnt lgkmcnt(0)" ::: "memory");   // before next pass overwrite
        __builtin_amdgcn_sched_barrier(0);

        #pragma unroll
        for (int cf = 0; cf < 4; ++cf) {
            const int c = cf * 16 + lr;
            #pragma unroll
            for (int r = 0; r < 4; ++r) {
                const int i = i0 + lg * 4 + r;
                Ob[(long long)(b * 256 + i) * 512 + h * 64 + c] = f2bf(o[cf][r]);
            }
        }
    }
}

// ---------------------------------------------------------------------------
// Narrow GEMM, m97 single-buffer structure, template BK (64 or 128 elems).
// Both-side 3-bit XOR slot swizzle; 4 waves (2x2), wave tile (BMt/2)x(BNt/2).
// OUT: 0 = bf16, 1 = fp32 + residual add, 2 = QKV split (cols<1024 -> bf16 C
// at ldc=1024; cols>=1024 -> V head-transposed scatter into C2 [b][c][a]).
template<int BMt, int BNt, int BKt, int NT, int OUT, bool RELU, bool SWZ>
__global__ __launch_bounds__(256, 4) void gemm_nar(
    const ushort* __restrict__ A, const ushort* __restrict__ B,
    const float* __restrict__ bias, const float* __restrict__ res,
    void* __restrict__ Cv, ushort* __restrict__ C2,
    int lda, int ldb, int ldc, int gx)
{
    constexpr int SL  = BKt / 8;            // 16B slots per LDS row
    constexpr int RPI = 2048 / BKt;         // rows staged per issue (256 thr)
    constexpr int AI  = BMt / RPI;
    constexpr int BI  = BNt / RPI;
    constexpr int HM = BMt / 2, HN = BNt / 2;
    constexpr int RM = HM / 16, RN = HN / 16;

    __shared__ ushort As[BMt * BKt];
    __shared__ ushort Bs[BNt * BKt];

    const int t = threadIdx.x;
    int nb, mb;
    if (SWZ) {
        const int nwg = gridDim.x, bid = blockIdx.x;
        const int swz = (bid & 7) * (nwg >> 3) + (bid >> 3);
        nb = swz % gx; mb = swz / gx;
    } else {
        nb = blockIdx.x; mb = blockIdx.y;
    }
    const int m0 = mb * BMt, n0 = nb * BNt;

    const int trow  = t / SL;
    const int tslot = (t % SL) ^ (trow & 7);
    const ushort* Ap = A + (long long)(m0 + trow) * lda + tslot * 8;
    const ushort* Bp = B + (long long)(n0 + trow) * ldb + tslot * 8;

    const int w = t >> 6, lane = t & 63;
    const int wr = w >> 1, wc = w & 1;
    const int lr = lane & 15, lg = lane >> 4;
    const int sx = lr & 7;

    f32x4_t acc[RM][RN];
    #pragma unroll
    for (int i = 0; i < RM; ++i)
        #pragma unroll
        for (int j = 0; j < RN; ++j)
            acc[i][j] = (f32x4_t){0.f, 0.f, 0.f, 0.f};

    for (int kt = 0; kt < NT; ++kt) {
        const long long ko = (long long)kt * BKt;
        #pragma unroll
        for (int i = 0; i < AI; ++i)
            gload16(Ap + ko + (long long)i * RPI * lda, &As[t * 8 + i * 2048]);
        #pragma unroll
        for (int i = 0; i < BI; ++i)
            gload16(Bp + ko + (long long)i * RPI * ldb, &Bs[t * 8 + i * 2048]);
        __syncthreads();

        #pragma unroll
        for (int kk = 0; kk < BKt / 32; ++kk) {
            bf16x8_t af[RM], bfr[RN];
            #pragma unroll
            for (int mf = 0; mf < RM; ++mf)
                af[mf] = *(const bf16x8_t*)
                    &As[(wr * HM + mf * 16 + lr) * BKt + (((kk * 4 + lg) ^ sx) * 8)];
            #pragma unroll
            for (int nf = 0; nf < RN; ++nf)
                bfr[nf] = *(const bf16x8_t*)
                    &Bs[(wc * HN + nf * 16 + lr) * BKt + (((kk * 4 + lg) ^ sx) * 8)];
            #pragma unroll
            for (int mf = 0; mf < RM; ++mf)
                #pragma unroll
                for (int nf = 0; nf < RN; ++nf)
                    acc[mf][nf] = __builtin_amdgcn_mfma_f32_16x16x32_bf16(
                        af[mf], bfr[nf], acc[mf][nf], 0, 0, 0);
        }
        __syncthreads();
    }

    #pragma unroll
    for (int nf = 0; nf < RN; ++nf) {
        const int col = n0 + wc * HN + nf * 16 + lr;
        const float bv = bias[col];
        #pragma unroll
        for (int mf = 0; mf < RM; ++mf) {
            const int row0 = m0 + wr * HM + mf * 16 + lg * 4;
            #pragma unroll
            for (int j = 0; j < 4; ++j) {
                float vv = acc[mf][nf][j] + bv;
                if (RELU) vv = fmaxf(vv, 0.0f);
                const int row = row0 + j;
                if (OUT == 0) {
                    ((ushort*)Cv)[(long long)row * ldc + col] = f2bf(vv);
                } else if (OUT == 1) {
                    const long long idx = (long long)row * ldc + col;
                    ((float*)Cv)[idx] = vv + res[idx];
                } else {   // QKV split
                    if (col < 1024) {
                        ((ushort*)Cv)[(long long)row * 1024 + col] = f2bf(vv);
                    } else {
                        const int bq_ = row >> 8, a_ = row & 255;
                        C2[(long long)bq_ * 131072 + (long long)(col - 1024) * 256 + a_] = f2bf(vv);
                    }
                }
            }
        }
    }
}

// ---------------------------------------------------------------------------
// Fused final-norm + edge heads: wave per row; h never hits memory.
__global__ __launch_bounds__(256) void ln_edge_kernel(
    const float* __restrict__ x, const float* __restrict__ alpha,
    const float* __restrict__ beta, const float* __restrict__ Wfl,
    float* __restrict__ L, float* __restrict__ R)
{
    const int row = blockIdx.x * 4 + (threadIdx.x >> 6);
    const int lane = threadIdx.x & 63;
    const float* xr = x + (long long)row * DD;
    float4 v0 = *(const float4*)&xr[lane * 8];
    float4 v1 = *(const float4*)&xr[lane * 8 + 4];
    float s  = v0.x + v0.y + v0.z + v0.w + v1.x + v1.y + v1.z + v1.w;
    float ss = v0.x*v0.x + v0.y*v0.y + v0.z*v0.z + v0.w*v0.w
             + v1.x*v1.x + v1.y*v1.y + v1.z*v1.z + v1.w*v1.w;
    #pragma unroll
    for (int off = 1; off < 64; off <<= 1) {
        s  += __shfl_xor(s, off, 64);
        ss += __shfl_xor(ss, off, 64);
    }
    float mu = s * (1.0f / 512.0f);
    float var = fmaxf(ss - 512.0f * mu * mu, 0.0f) * (1.0f / 511.0f);
    float inv = 1.0f / (sqrtf(var) + 1e-6f);

    float h[8];
    {
        float4 a0 = *(const float4*)&alpha[lane * 8];
        float4 a1 = *(const float4*)&alpha[lane * 8 + 4];
        float4 b0 = *(const float4*)&beta[lane * 8];
        float4 b1 = *(const float4*)&beta[lane * 8 + 4];
        h[0] = a0.x * (v0.x - mu) * inv + b0.x;
        h[1] = a0.y * (v0.y - mu) * inv + b0.y;
        h[2] = a0.z * (v0.z - mu) * inv + b0.z;
        h[3] = a0.w * (v0.w - mu) * inv + b0.w;
        h[4] = a1.x * (v1.x - mu) * inv + b1.x;
        h[5] = a1.y * (v1.y - mu) * inv + b1.y;
        h[6] = a1.z * (v1.z - mu) * inv + b1.z;
        h[7] = a1.w * (v1.w - mu) * inv + b1.w;
    }
    float accL[NB] = {}, accR[NB] = {};
    #pragma unroll
    for (int tt = 0; tt < 8; ++tt) {
        const int e = lane * 8 + tt;
        float4 wl = *(const float4*)&Wfl[e * NB];
        float4 wr = *(const float4*)&Wfl[(DD + e) * NB];
        accL[0] = fmaf(h[tt], wl.x, accL[0]);
        accL[1] = fmaf(h[tt], wl.y, accL[1]);
        accL[2] = fmaf(h[tt], wl.z, accL[2]);
        accL[3] = fmaf(h[tt], wl.w, accL[3]);
        accR[0] = fmaf(h[tt], wr.x, accR[0]);
        accR[1] = fmaf(h[tt], wr.y, accR[1]);
        accR[2] = fmaf(h[tt], wr.z, accR[2]);
        accR[3] = fmaf(h[tt], wr.w, accR[3]);
    }
    #pragma unroll
    for (int n = 0; n < NB; ++n) {
        #pragma unroll
        for (int off = 1; off < 64; off <<= 1) {
            accL[n] += __shfl_xor(accL[n], off, 64);
            accR[n] += __shfl_xor(accR[n], off, 64);
        }
    }
    if (lane == 0) {
        #pragma unroll
        for (int n = 0; n < NB; ++n) {
            L[row * NB + n] = accL[n];
            R[row * NB + n] = accR[n];
        }
    }
}

__global__ __launch_bounds__(256) void edge_combine_kernel(
    const float* __restrict__ L, const float* __restrict__ R,
    const float* __restrict__ bfl, float* __restrict__ out)
{
    int idx = blockIdx.x * 256 + threadIdx.x;
    int j = idx & 255;
    int bi = idx >> 8;
    int b = bi >> 8;
    float4 l = *(const float4*)&L[bi * NB];
    float4 r = *(const float4*)&R[(b * 256 + j) * NB];
    float4 bf = *(const float4*)bfl;
    float4 o;
    o.x = l.x + r.x + bf.x; o.y = l.y + r.y + bf.y;
    o.z = l.z + r.z + bf.z; o.w = l.w + r.w + bf.w;
    *(float4*)&out[(long long)idx * NB] = o;
}

// ---------------------------------------------------------------------------
extern "C" void kernel_launch(void* const* d_in, const int* in_sizes, int n_in,
                              void* d_out, int out_size, void* d_ws, size_t ws_size,
                              hipStream_t stream)
{
    const int*   src   = (const int*)  d_in[0];
    const float* pe    = (const float*)d_in[3];
    const float* emb   = (const float*)d_in[4];
    const float* Wq    = (const float*)d_in[5];
    const float* Wk    = (const float*)d_in[6];
    const float* Wv    = (const float*)d_in[7];
    const float* Wo    = (const float*)d_in[8];
    const float* W1    = (const float*)d_in[9];
    const float* W2    = (const float*)d_in[10];
    const float* Wfl   = (const float*)d_in[11];
    const float* bq    = (const float*)d_in[12];
    const float* bk    = (const float*)d_in[13];
    const float* bv    = (const float*)d_in[14];
    const float* bo    = (const float*)d_in[15];
    const float* b1    = (const float*)d_in[16];
    const float* b2    = (const float*)d_in[17];
    const float* ln1_b = (const float*)d_in[18];
    const float* ln2_b = (const float*)d_in[19];
    const float* fn_b  = (const float*)d_in[20];
    const float* bfl   = (const float*)d_in[21];
    const float* ln1_a = (const float*)d_in[22];
    const float* ln2_a = (const float*)d_in[23];
    const float* fn_a  = (const float*)d_in[24];
    float* out = (float*)d_out;

    const long long ROWS = (long long)BB * AA;   // 8192
    char* p = (char*)d_ws;
    float*  x    = (float*)p;  p += ROWS * DD * 4;                 // 16 MB
    ushort* x2b  = (ushort*)p; p += ROWS * DD * 2;                 // 8 MB (LN out / attn out)
    ushort* qk   = (ushort*)p;                                     // 16 MB [row][1024]
    ushort* h1   = qk;                                             // h1 aliases qk+vT+pad (32 MB)
    p += ROWS * 1024 * 2;
    ushort* vT   = (ushort*)p; p += (long long)BB * DD * AA * 2;   // 8 MB [b][c][a]
    p += 8 * 1024 * 1024;                                          // pad so h1 fits 32 MB
    ushort* Wqkvt= (ushort*)p; p += (long long)NLAYER * 1536 * 512 * 2;
    ushort* Wot  = (ushort*)p; p += (long long)NLAYER * 512 * 512 * 2;
    ushort* W1t  = (ushort*)p; p += (long long)NLAYER * 2048 * 512 * 2;
    ushort* W2t  = (ushort*)p; p += (long long)NLAYER * 512 * 2048 * 2;
    float*  bqkv = (float*)p;  p += (long long)NLAYER * 1536 * 4;
    float*  left = (float*)p;  p += ROWS * NB * 4;
    float*  right= (float*)p;  p += ROWS * NB * 4;

    // ---- weight prep (bf16, K-major) ----
    wtrans4_kernel<<<dim3(8, 8, 24), 256, 0, stream>>>(Wq, Wk, Wv, Wo, Wqkvt, Wot);
    wtrans_kernel<<<dim3(32, 8, 6), 256, 0, stream>>>(W1, W1t, 2048, 512,  1048576LL, 1048576LL);
    wtrans_kernel<<<dim3(8, 32, 6), 256, 0, stream>>>(W2, W2t, 512,  2048, 1048576LL, 1048576LL);
    concat_bias_kernel<<<36, 256, 0, stream>>>(bq, bk, bv, bqkv);

    // ---- embed + PE ----
    embed_pe_kernel<<<4096, 256, 0, stream>>>(src, emb, pe, x);

    for (int i = 0; i < NLAYER; ++i) {
        // LN1 -> bf16
        layernorm512_kernel<true><<<2048, 256, 0, stream>>>(
            x, ln1_a + i * DD, ln1_b + i * DD, x2b);
        // fused QKV projection with V-transpose epilogue: 128x128, BK=64 (NT=8)
        gemm_nar<128, 128, 64, 8, 2, false, true><<<768, 256, 0, stream>>>(
            x2b, Wqkvt + (long long)i * 786432, bqkv + i * 1536, nullptr,
            qk, vT, 512, 512, 1024, 12);
        // fused attention (QK^T + softmax + PV) -> x2b
        attn_kernel<<<256, 512, 0, stream>>>(qk, vT, x2b);
        // x += O@Wo + bo : 128x64, BK=64 (NT=8)
        gemm_nar<128, 64, 64, 8, 1, false, true><<<512, 256, 0, stream>>>(
            x2b, Wot + (long long)i * 262144, bo + i * DD, x,
            x, nullptr, 512, 512, 512, 8);
        // LN2 -> bf16
        layernorm512_kernel<true><<<2048, 256, 0, stream>>>(
            x, ln2_a + i * DD, ln2_b + i * DD, x2b);
        // h1 = relu(x2@W1 + b1): 128x128, BK=64 (NT=8), grid 1024 (4/CU)
        gemm_nar<128, 128, 64, 8, 0, true, true><<<1024, 256, 0, stream>>>(
            x2b, W1t + (long long)i * 1048576, b1 + i * DFF, nullptr,
            h1, nullptr, 512, 512, 2048, 16);
        // x += h1@W2 + b2 : 64x64, BK=128 (NT=16), grid 1024 (4/CU)
        gemm_nar<64, 64, 128, 16, 1, false, true><<<1024, 256, 0, stream>>>(
            h1, W2t + (long long)i * 1048576, b2 + i * DD, x,
            x, nullptr, 2048, 2048, 512, 8);
    }

    // fused final norm + edge heads, then combine
    ln_edge_kernel<<<2048, 256, 0, stream>>>(x, fn_a, fn_b, Wfl, left, right);
    edge_combine_kernel<<<8192, 256, 0, stream>>>(left, right, bfl, out);
}